// Round 5
// baseline (795.715 us; speedup 1.0000x reference)
//
#include <hip/hip_runtime.h>

typedef __bf16 bf16;
typedef __bf16 bf16x4 __attribute__((ext_vector_type(4)));
typedef __bf16 bf16x8 __attribute__((ext_vector_type(8)));
typedef float f32x4 __attribute__((ext_vector_type(4)));

#define D_   1024
#define S_   1024
#define B_   2
#define NTOK 2048
#define FF_  4096
#define NE   8
#define CAP  5120
#define OUTN 2097152

// fast tanh-form GELU: one v_exp_f32 instead of libm tanhf.
__device__ __forceinline__ float gelu_f(float x) {
    float u = 0.7978845608028654f * (x + 0.044715f * x * x * x);
    float a = fabsf(u);
    float e = __expf(-2.0f * a);
    float t = (1.0f - e) / (1.0f + e);
    t = copysignf(t, u);
    return 0.5f * x * (1.0f + t);
}

// async global->LDS, 16B per lane. LDS dest must be wave-uniform base; HW adds lane*16.
__device__ __forceinline__ void gload16(const void* g, void* l) {
    __builtin_amdgcn_global_load_lds((const __attribute__((address_space(1))) unsigned int*)g,
                                     (__attribute__((address_space(3))) unsigned int*)l,
                                     16, 0, 0);
}

// counted vmem wait (T4): keep N loads in flight across the barrier.
#define VMCNT(n) asm volatile("s_waitcnt vmcnt(" n ")" ::: "memory")
// raw barrier with compiler-level memory fences (no vmcnt(0) drain).
#define BARRIER() do { asm volatile("" ::: "memory"); \
                       __builtin_amdgcn_s_barrier();  \
                       asm volatile("" ::: "memory"); } while (0)

// ---------------------------------------------------------------------------
// RMSNorm: one block per row of 1024. Optional fp32 / bf16-hi / bf16-lo outs.
// ---------------------------------------------------------------------------
__global__ __launch_bounds__(256) void rmsnorm_k(const float* __restrict__ x,
                                                 const float* __restrict__ w,
                                                 float* __restrict__ yf,
                                                 bf16* __restrict__ yhi,
                                                 bf16* __restrict__ ylo) {
    int row = blockIdx.x;
    int t = threadIdx.x;
    const float* xr = x + (size_t)row * D_;
    float4 v = *(const float4*)(xr + t * 4);
    float ss = v.x * v.x + v.y * v.y + v.z * v.z + v.w * v.w;
    for (int off = 32; off; off >>= 1) ss += __shfl_down(ss, off);
    __shared__ float wsum[4];
    if ((t & 63) == 0) wsum[t >> 6] = ss;
    __syncthreads();
    float tot = wsum[0] + wsum[1] + wsum[2] + wsum[3];
    float rr = rsqrtf(tot * (1.0f / D_) + 1e-6f);
    float4 wv = *(const float4*)(w + t * 4);
    float y[4];
    y[0] = v.x * rr * wv.x; y[1] = v.y * rr * wv.y;
    y[2] = v.z * rr * wv.z; y[3] = v.w * rr * wv.w;
    if (yf) *(float4*)(yf + (size_t)row * D_ + t * 4) = *(float4*)y;
    if (yhi) {
#pragma unroll
        for (int i = 0; i < 4; i++) {
            bf16 hi = (bf16)y[i];
            yhi[(size_t)row * D_ + t * 4 + i] = hi;
            if (ylo) ylo[(size_t)row * D_ + t * 4 + i] = (bf16)(y[i] - (float)hi);
        }
    }
}

// ---------------------------------------------------------------------------
// Transpose + split-cast fp32 [1024][1024] -> bf16 hi/lo [N][K]. (attn weights)
// ---------------------------------------------------------------------------
__global__ __launch_bounds__(256) void trans_split_k(
    const float* __restrict__ w0, const float* __restrict__ w1p,
    const float* __restrict__ w2p, const float* __restrict__ w3,
    bf16* o0h, bf16* o0l, bf16* o1h, bf16* o1l,
    bf16* o2h, bf16* o2l, bf16* o3h, bf16* o3l) {
    int z = blockIdx.z;
    const float* src = (z == 0) ? w0 : (z == 1) ? w1p : (z == 2) ? w2p : w3;
    bf16* dh = (z == 0) ? o0h : (z == 1) ? o1h : (z == 2) ? o2h : o3h;
    bf16* dl = (z == 0) ? o0l : (z == 1) ? o1l : (z == 2) ? o2l : o3l;
    __shared__ float tl[32][33];
    int c0 = blockIdx.x * 32, r0 = blockIdx.y * 32;
    int tx = threadIdx.x & 31, ty = threadIdx.x >> 5;
#pragma unroll
    for (int i = 0; i < 4; i++) {
        int r = ty + i * 8;
        tl[r][tx] = src[(size_t)(r0 + r) * 1024 + c0 + tx];
    }
    __syncthreads();
#pragma unroll
    for (int i = 0; i < 4; i++) {
        int c = ty + i * 8;
        float v = tl[tx][c];
        bf16 hi = (bf16)v;
        dh[(size_t)(c0 + c) * 1024 + r0 + tx] = hi;
        dl[(size_t)(c0 + c) * 1024 + r0 + tx] = (bf16)(v - (float)hi);
    }
}

// ---------------------------------------------------------------------------
// Vectorized transpose + cast fp32 -> bf16: in [z][R][C] -> out [z][C][R].
// 64x64 tile, float4 loads (16B/lane), bf16x4 stores (8B/lane).  (MoE weights)
// ---------------------------------------------------------------------------
__global__ __launch_bounds__(256) void transpose_cast4_k(const float* __restrict__ in,
                                                         bf16* __restrict__ out,
                                                         int R, int C) {
    __shared__ float tl[64][65];
    size_t base = (size_t)blockIdx.z * R * C;
    const float* src = in + base;
    bf16* dst = out + base;
    int c0 = blockIdx.x * 64, r0 = blockIdx.y * 64;
    int t = threadIdx.x;
    int lr = t >> 4;            // 0..15
    int lc = (t & 15) * 4;      // 0,4,..,60
#pragma unroll
    for (int i = 0; i < 4; i++) {
        int r = lr + i * 16;
        float4 v = *(const float4*)(src + (size_t)(r0 + r) * C + c0 + lc);
        tl[r][lc] = v.x; tl[r][lc + 1] = v.y; tl[r][lc + 2] = v.z; tl[r][lc + 3] = v.w;
    }
    __syncthreads();
    int wc = t >> 4;            // col 0..15 (+16*i)
    int wr = (t & 15) * 4;      // row chunk 0,4,..,60
#pragma unroll
    for (int i = 0; i < 4; i++) {
        int c = wc + i * 16;
        bf16x4 o;
        o[0] = (bf16)tl[wr][c];     o[1] = (bf16)tl[wr + 1][c];
        o[2] = (bf16)tl[wr + 2][c]; o[3] = (bf16)tl[wr + 3][c];
        *(bf16x4*)(dst + (size_t)(c0 + c) * R + r0 + wr) = o;
    }
}

// ---------------------------------------------------------------------------
// Split-bf16 dense GEMM, 128x128 tile, BK=32, 4 waves 2x2, K=1024.
// (attention-path weights) — unchanged for attribution.
// ---------------------------------------------------------------------------
#define SPLIT_STAGE(bi, k0)                             \
    gload16(gah0 + (k0), Lah[bi] + wv * 512);           \
    gload16(gah1 + (k0), Lah[bi] + 2048 + wv * 512);    \
    gload16(gal0 + (k0), Lal[bi] + wv * 512);           \
    gload16(gal1 + (k0), Lal[bi] + 2048 + wv * 512);    \
    gload16(gbh0 + (k0), Lbh[bi] + wv * 512);           \
    gload16(gbh1 + (k0), Lbh[bi] + 2048 + wv * 512);    \
    gload16(gbl0 + (k0), Lbl[bi] + wv * 512);           \
    gload16(gbl1 + (k0), Lbl[bi] + 2048 + wv * 512);

#define SPLIT_COMPUTE(bi) {                                                            \
    bf16x8 fah[4], fal[4], fbh[4], fbl[4];                                             \
    _Pragma("unroll") for (int i = 0; i < 4; i++) {                                    \
        fah[i] = *(const bf16x8*)(Lah[bi] + ra_off[i]);                                \
        fal[i] = *(const bf16x8*)(Lal[bi] + ra_off[i]);                                \
        fbh[i] = *(const bf16x8*)(Lbh[bi] + rb_off[i]);                                \
        fbl[i] = *(const bf16x8*)(Lbl[bi] + rb_off[i]);                                \
    }                                                                                  \
    _Pragma("unroll") for (int mt = 0; mt < 4; mt++)                                   \
    _Pragma("unroll") for (int nt = 0; nt < 4; nt++) {                                 \
        acc[mt][nt] = __builtin_amdgcn_mfma_f32_16x16x32_bf16(fah[mt], fbh[nt], acc[mt][nt], 0, 0, 0); \
        acc[mt][nt] = __builtin_amdgcn_mfma_f32_16x16x32_bf16(fah[mt], fbl[nt], acc[mt][nt], 0, 0, 0); \
        acc[mt][nt] = __builtin_amdgcn_mfma_f32_16x16x32_bf16(fal[mt], fbh[nt], acc[mt][nt], 0, 0, 0); \
    } }

#define GEMM128_SPLIT_BODY(EPILOGUE)                                                   \
    __shared__ __align__(16) bf16 Lah[2][4096];                                        \
    __shared__ __align__(16) bf16 Lal[2][4096];                                        \
    __shared__ __align__(16) bf16 Lbh[2][4096];                                        \
    __shared__ __align__(16) bf16 Lbl[2][4096];                                        \
    int t = threadIdx.x;                                                               \
    int wv = t >> 6, ln = t & 63;                                                      \
    int wm = wv >> 1, wn = wv & 1, l15 = ln & 15, qd = ln >> 4;                        \
    int sr0 = t >> 2, sr1 = 64 + sr0, cl = t & 3;                                      \
    int cs0 = (cl ^ ((sr0 >> 1) & 3)) * 8;                                             \
    int cs1 = (cl ^ ((sr1 >> 1) & 3)) * 8;                                             \
    const bf16* gah0 = Ah + (size_t)(m0 + sr0) * 1024 + cs0;                           \
    const bf16* gah1 = Ah + (size_t)(m0 + sr1) * 1024 + cs1;                           \
    const bf16* gal0 = Al + (size_t)(m0 + sr0) * 1024 + cs0;                           \
    const bf16* gal1 = Al + (size_t)(m0 + sr1) * 1024 + cs1;                           \
    const bf16* gbh0 = Bh + (size_t)(n0 + sr0) * 1024 + cs0;                           \
    const bf16* gbh1 = Bh + (size_t)(n0 + sr1) * 1024 + cs1;                           \
    const bf16* gbl0 = Bl + (size_t)(n0 + sr0) * 1024 + cs0;                           \
    const bf16* gbl1 = Bl + (size_t)(n0 + sr1) * 1024 + cs1;                           \
    int ra_off[4], rb_off[4];                                                          \
    _Pragma("unroll") for (int i = 0; i < 4; i++) {                                    \
        int r1 = wm * 64 + i * 16 + l15;                                               \
        ra_off[i] = r1 * 32 + (qd ^ ((r1 >> 1) & 3)) * 8;                              \
        int r2 = wn * 64 + i * 16 + l15;                                               \
        rb_off[i] = r2 * 32 + (qd ^ ((r2 >> 1) & 3)) * 8;                              \
    }                                                                                  \
    f32x4 acc[4][4];                                                                   \
    _Pragma("unroll") for (int mt = 0; mt < 4; mt++)                                   \
    _Pragma("unroll") for (int nt = 0; nt < 4; nt++) acc[mt][nt] = (f32x4){0.f,0.f,0.f,0.f}; \
    SPLIT_STAGE(0, 0);                                                                 \
    __syncthreads();                                                                   \
    for (int k0 = 0; k0 < 1024; k0 += 64) {                                            \
        SPLIT_STAGE(1, k0 + 32);                                                       \
        SPLIT_COMPUTE(0);                                                              \
        __syncthreads();                                                               \
        if (k0 + 64 < 1024) { SPLIT_STAGE(0, k0 + 64); }                               \
        SPLIT_COMPUTE(1);                                                              \
        __syncthreads();                                                               \
    }                                                                                  \
    _Pragma("unroll") for (int mt = 0; mt < 4; mt++)                                   \
    _Pragma("unroll") for (int nt = 0; nt < 4; nt++)                                   \
        _Pragma("unroll") for (int r = 0; r < 4; r++) {                                \
            int gm = m0 + wm * 64 + mt * 16 + qd * 4 + r;                              \
            int gn = n0 + wn * 64 + nt * 16 + l15;                                     \
            float vv = acc[mt][nt][r];                                                 \
            EPILOGUE                                                                   \
        }

// QKV: grid (16, 24): y = weight*8 + n-tile. Outputs split hi/lo.
__global__ __launch_bounds__(256) void gemm_qkv_k(
    const bf16* __restrict__ Ah, const bf16* __restrict__ Al,
    const bf16* __restrict__ Bqh, const bf16* __restrict__ Bql,
    const bf16* __restrict__ Bkh, const bf16* __restrict__ Bkl,
    const bf16* __restrict__ Bvh, const bf16* __restrict__ Bvl,
    bf16* Cqh, bf16* Cql, bf16* Ckh, bf16* Ckl, bf16* Cvh, bf16* Cvl) {
    int gy = blockIdx.y, zw = gy >> 3;
    const bf16* Bh = (zw == 0) ? Bqh : (zw == 1) ? Bkh : Bvh;
    const bf16* Bl = (zw == 0) ? Bql : (zw == 1) ? Bkl : Bvl;
    bf16* Ch = (zw == 0) ? Cqh : (zw == 1) ? Ckh : Cvh;
    bf16* Cl = (zw == 0) ? Cql : (zw == 1) ? Ckl : Cvl;
    int m0 = blockIdx.x * 128, n0 = (gy & 7) * 128;
    GEMM128_SPLIT_BODY({
        bf16 hi = (bf16)vv;
        Ch[(size_t)gm * D_ + gn] = hi;
        Cl[(size_t)gm * D_ + gn] = (bf16)(vv - (float)hi);
    })
}

// WO: grid (16, 8): C = X + A@B (direct fp32 store).
__global__ __launch_bounds__(256) void gemm_wo_k(
    const bf16* __restrict__ Ah, const bf16* __restrict__ Al,
    const bf16* __restrict__ Bh, const bf16* __restrict__ Bl,
    float* __restrict__ C, const float* __restrict__ X) {
    int m0 = blockIdx.x * 128, n0 = blockIdx.y * 128;
    GEMM128_SPLIT_BODY({
        C[(size_t)gm * D_ + gn] = X[(size_t)gm * D_ + gn] + vv;
    })
}

// ---------------------------------------------------------------------------
// Split-bf16 MFMA flash attention. Block = (qt desc, h, b): 64 q-rows, 4 waves.
// ---------------------------------------------------------------------------
#define AP 72

__global__ __launch_bounds__(256) void attn_mfma_k(
    const bf16* __restrict__ qhp, const bf16* __restrict__ qlp,
    const bf16* __restrict__ khp, const bf16* __restrict__ klp,
    const bf16* __restrict__ vhp, const bf16* __restrict__ vlp,
    bf16* __restrict__ aoh, bf16* __restrict__ aol) {
    int qt = (int)gridDim.x - 1 - (int)blockIdx.x;  // deep tiles first
    int h = blockIdx.y, b = blockIdx.z;
    __shared__ bf16 Ksh[64 * AP], Ksl[64 * AP], VTh[64 * AP], VTl[64 * AP];
    __shared__ bf16 Ph[4][16 * AP], Pl[4][16 * AP];
    int t = threadIdx.x, wv = t >> 6, ln = t & 63, l15 = ln & 15, qd = ln >> 4;

    bf16x8 aqh[2], aql[2];
    {
        size_t qb = ((size_t)(b * S_ + qt * 64 + wv * 16 + l15)) * D_ + h * 64 + qd * 8;
        aqh[0] = *(const bf16x8*)(qhp + qb);
        aqh[1] = *(const bf16x8*)(qhp + qb + 32);
        aql[0] = *(const bf16x8*)(qlp + qb);
        aql[1] = *(const bf16x8*)(qlp + qb + 32);
    }
    f32x4 oacc[4];
    float mrow[4], lrow[4];
#pragma unroll
    for (int i = 0; i < 4; i++) {
        oacc[i] = (f32x4){0.f, 0.f, 0.f, 0.f};
        mrow[i] = -1e30f; lrow[i] = 0.0f;
    }

    for (int kt = 0; kt <= qt; kt++) {
        __syncthreads();
#pragma unroll
        for (int j = 0; j < 2; j++) {
            int idx = t + j * 256;
            int row = idx >> 3, ch = (idx & 7) * 8;
            size_t g = ((size_t)(b * S_ + kt * 64 + row)) * D_ + h * 64 + ch;
            *(bf16x8*)&Ksh[row * AP + ch] = *(const bf16x8*)(khp + g);
            *(bf16x8*)&Ksl[row * AP + ch] = *(const bf16x8*)(klp + g);
            bf16x8 vvh = *(const bf16x8*)(vhp + g);
            bf16x8 vvl = *(const bf16x8*)(vlp + g);
#pragma unroll
            for (int jj = 0; jj < 8; jj++) {
                VTh[(ch + jj) * AP + row] = vvh[jj];
                VTl[(ch + jj) * AP + row] = vvl[jj];
            }
        }
        __syncthreads();

        f32x4 sacc[4];
#pragma unroll
        for (int nt = 0; nt < 4; nt++) sacc[nt] = (f32x4){0.f, 0.f, 0.f, 0.f};
#pragma unroll
        for (int ks = 0; ks < 2; ks++) {
#pragma unroll
            for (int nt = 0; nt < 4; nt++) {
                bf16x8 bh = *(const bf16x8*)&Ksh[(nt * 16 + l15) * AP + ks * 32 + qd * 8];
                bf16x8 bl = *(const bf16x8*)&Ksl[(nt * 16 + l15) * AP + ks * 32 + qd * 8];
                sacc[nt] = __builtin_amdgcn_mfma_f32_16x16x32_bf16(aqh[ks], bh, sacc[nt], 0, 0, 0);
                sacc[nt] = __builtin_amdgcn_mfma_f32_16x16x32_bf16(aqh[ks], bl, sacc[nt], 0, 0, 0);
                sacc[nt] = __builtin_amdgcn_mfma_f32_16x16x32_bf16(aql[ks], bh, sacc[nt], 0, 0, 0);
            }
        }
        bool diag = (kt == qt);
#pragma unroll
        for (int r = 0; r < 4; r++) {
            float s0[4];
#pragma unroll
            for (int nt = 0; nt < 4; nt++) {
                s0[nt] = sacc[nt][r] * 0.125f;
                if (diag && (nt * 16 + l15) > (wv * 16 + qd * 4 + r)) s0[nt] = -1e30f;
            }
            float vmax = fmaxf(fmaxf(s0[0], s0[1]), fmaxf(s0[2], s0[3]));
            for (int off = 1; off < 16; off <<= 1) vmax = fmaxf(vmax, __shfl_xor(vmax, off));
            float mnew = fmaxf(mrow[r], vmax);
            float alpha = __expf(mrow[r] - mnew);
            float p[4], rs = 0.0f;
#pragma unroll
            for (int nt = 0; nt < 4; nt++) { p[nt] = __expf(s0[nt] - mnew); rs += p[nt]; }
            for (int off = 1; off < 16; off <<= 1) rs += __shfl_xor(rs, off);
            lrow[r] = lrow[r] * alpha + rs;
            mrow[r] = mnew;
#pragma unroll
            for (int nt = 0; nt < 4; nt++) oacc[nt][r] *= alpha;
            int prow = qd * 4 + r;
#pragma unroll
            for (int nt = 0; nt < 4; nt++) {
                bf16 hi = (bf16)p[nt];
                Ph[wv][prow * AP + nt * 16 + l15] = hi;
                Pl[wv][prow * AP + nt * 16 + l15] = (bf16)(p[nt] - (float)hi);
            }
        }
        // PV: same-wave LDS RAW (in-order DS pipe), no barrier needed.
#pragma unroll
        for (int ks2 = 0; ks2 < 2; ks2++) {
            bf16x8 aph = *(const bf16x8*)&Ph[wv][l15 * AP + ks2 * 32 + qd * 8];
            bf16x8 apl = *(const bf16x8*)&Pl[wv][l15 * AP + ks2 * 32 + qd * 8];
#pragma unroll
            for (int nt = 0; nt < 4; nt++) {
                bf16x8 bvh = *(const bf16x8*)&VTh[(nt * 16 + l15) * AP + ks2 * 32 + qd * 8];
                bf16x8 bvl = *(const bf16x8*)&VTl[(nt * 16 + l15) * AP + ks2 * 32 + qd * 8];
                oacc[nt] = __builtin_amdgcn_mfma_f32_16x16x32_bf16(aph, bvh, oacc[nt], 0, 0, 0);
                oacc[nt] = __builtin_amdgcn_mfma_f32_16x16x32_bf16(aph, bvl, oacc[nt], 0, 0, 0);
                oacc[nt] = __builtin_amdgcn_mfma_f32_16x16x32_bf16(apl, bvh, oacc[nt], 0, 0, 0);
            }
        }
    }

#pragma unroll
    for (int r = 0; r < 4; r++) {
        float inv = 1.0f / lrow[r];
        size_t rowa = ((size_t)(b * S_ + qt * 64 + wv * 16 + qd * 4 + r)) * D_ + h * 64;
#pragma unroll
        for (int nt = 0; nt < 4; nt++) {
            float o = oacc[nt][r] * inv;
            bf16 hi = (bf16)o;
            aoh[rowa + nt * 16 + l15] = hi;
            aol[rowa + nt * 16 + l15] = (bf16)(o - (float)hi);
        }
    }
}

// ---------------------------------------------------------------------------
// Router: 4 tokens/block (wave each). fp32 logits -> softmax -> top2.
// ---------------------------------------------------------------------------
__global__ __launch_bounds__(256) void router_k(const float* __restrict__ h,
                                                const float* __restrict__ rw,
                                                int* __restrict__ tidx,
                                                float* __restrict__ tgate,
                                                int* __restrict__ ecnt,
                                                float* __restrict__ psum) {
    int wv = threadIdx.x >> 6, ln = threadIdx.x & 63;
    int tok = blockIdx.x * 4 + wv;
    const float* hr = h + (size_t)tok * D_;
    float acc[NE];
#pragma unroll
    for (int e = 0; e < NE; e++) acc[e] = 0.0f;
    int base = ln * 16;
#pragma unroll
    for (int c = 0; c < 4; c++) {
        float4 hv = *(const float4*)(hr + base + c * 4);
        const float* rp = rw + (size_t)(base + c * 4) * NE;
        float hx[4] = {hv.x, hv.y, hv.z, hv.w};
#pragma unroll
        for (int jj = 0; jj < 4; jj++)
#pragma unroll
            for (int e = 0; e < NE; e++)
                acc[e] = fmaf(hx[jj], rp[jj * NE + e], acc[e]);
    }
#pragma unroll
    for (int e = 0; e < NE; e++)
        for (int off = 32; off; off >>= 1) acc[e] += __shfl_down(acc[e], off);

    __shared__ float pb[4][NE];
    if (ln == 0) {
        float mx = acc[0];
#pragma unroll
        for (int e = 1; e < NE; e++) mx = fmaxf(mx, acc[e]);
        float p[NE], ssum = 0.0f;
#pragma unroll
        for (int e = 0; e < NE; e++) { p[e] = expf(acc[e] - mx); ssum += p[e]; }
        float inv = 1.0f / ssum;
#pragma unroll
        for (int e = 0; e < NE; e++) p[e] *= inv;
        int i0 = 0; float b0 = p[0];
#pragma unroll
        for (int e = 1; e < NE; e++) if (p[e] > b0) { b0 = p[e]; i0 = e; }
        int i1 = -1; float b1v = -1.0f;
#pragma unroll
        for (int e = 0; e < NE; e++) if (e != i0 && p[e] > b1v) { b1v = p[e]; i1 = e; }
        tidx[tok * 2] = i0; tidx[tok * 2 + 1] = i1;
        tgate[tok * 2] = b0; tgate[tok * 2 + 1] = b1v;
        atomicAdd(&ecnt[i0], 1);
        atomicAdd(&ecnt[i1], 1);
#pragma unroll
        for (int e = 0; e < NE; e++) pb[wv][e] = p[e];
    }
    __syncthreads();
    if (threadIdx.x < NE) {
        float s2 = pb[0][threadIdx.x] + pb[1][threadIdx.x] + pb[2][threadIdx.x] + pb[3][threadIdx.x];
        atomicAdd(&psum[threadIdx.x], s2);
    }
}

__global__ void passb_k(const int* __restrict__ ecnt, const float* __restrict__ psum,
                        int* __restrict__ eoffp, int* __restrict__ ecnt2,
                        float* __restrict__ out_tail) {
    if (threadIdx.x == 0) {
        int off = 0; float loss = 0.0f;
        for (int e = 0; e < NE; e++) {
            eoffp[e] = off;
            int c = ecnt[e];
            off += (c + 127) & ~127;
            loss += (c * (1.0f / 4096.0f)) * (psum[e] * (1.0f / 2048.0f));
            out_tail[1 + e] = (float)c;
            ecnt2[e] = 0;
        }
        eoffp[NE] = off;
        out_tail[0] = 8.0f * loss;
    }
}

// scatter: slot list per expert + inverse map (slot of each (tok,k)).
__global__ __launch_bounds__(256) void scatter_k(const int* __restrict__ tidx,
                                                 const int* __restrict__ eoffp,
                                                 int* __restrict__ ecnt2,
                                                 int* __restrict__ stok,
                                                 int* __restrict__ sidx) {
    int tok = blockIdx.x * 256 + threadIdx.x;
    for (int k = 0; k < 2; k++) {
        int e = tidx[tok * 2 + k];
        int pos = eoffp[e] + atomicAdd(&ecnt2[e], 1);
        stok[pos] = tok;
        sidx[tok * 2 + k] = pos;
    }
}

// ---------------------------------------------------------------------------
// MoE GEMMs with T4 counted-vmcnt pipelining. Both-sides XOR swizzle; linear LDS.
// ---------------------------------------------------------------------------
#define MOE_STAGE(bufA, bufB, k0)                       \
    gload16(ga0 + (k0), (bufA) + wv * 512);             \
    gload16(ga1 + (k0), (bufA) + 2048 + wv * 512);      \
    gload16(gb0 + (k0), (bufB) + wv * 512);             \
    gload16(gb1 + (k0), (bufB) + 2048 + wv * 512);

#define MOE_TILE(bufA, bufB) {                                                         \
    bf16x8 af[4], bfr[4];                                                              \
    _Pragma("unroll") for (int i = 0; i < 4; i++) {                                    \
        af[i]  = *(const bf16x8*)((bufA) + ra_off[i]);                                 \
        bfr[i] = *(const bf16x8*)((bufB) + rb_off[i]);                                 \
    }                                                                                  \
    _Pragma("unroll") for (int mt = 0; mt < 4; mt++)                                   \
    _Pragma("unroll") for (int nt = 0; nt < 4; nt++)                                   \
        acc[mt][nt] = __builtin_amdgcn_mfma_f32_16x16x32_bf16(af[mt], bfr[nt], acc[mt][nt], 0, 0, 0); }

#define MOE_STEP(rdA, rdB, VM)      \
    VMCNT(VM);                      \
    BARRIER();                      \
    MOE_TILE(rdA, rdB);             \
    BARRIER();

// GEMM1: K=1024 (32 tiles), 2 buffers depth-1. Grid (40,32)=1280 blocks (5/CU).
__global__ __launch_bounds__(256) void moe_gemm1_k(const bf16* __restrict__ hB,
                                                   const bf16* __restrict__ w1t,
                                                   const float* __restrict__ b1,
                                                   const int* __restrict__ eoffp,
                                                   const int* __restrict__ stok,
                                                   bf16* __restrict__ act) {
    int m0 = blockIdx.x * 128, n0 = blockIdx.y * 128;
    if (m0 >= eoffp[NE]) return;
    int e = 0;
#pragma unroll
    for (int i = 1; i < NE; i++) if (m0 >= eoffp[i]) e = i;

    __shared__ __align__(16) bf16 As[2][4096];
    __shared__ __align__(16) bf16 Bs[2][4096];
    int t = threadIdx.x;
    int wv = t >> 6, ln = t & 63;
    int wm = wv >> 1, wn = wv & 1, l15 = ln & 15, qd = ln >> 4;

    int sr0 = t >> 2, sr1 = 64 + sr0, cl = t & 3;
    int cs0 = (cl ^ ((sr0 >> 1) & 3)) * 8;
    int cs1 = (cl ^ ((sr1 >> 1) & 3)) * 8;
    const bf16* ga0 = hB + (size_t)stok[m0 + sr0] * D_ + cs0;
    const bf16* ga1 = hB + (size_t)stok[m0 + sr1] * D_ + cs1;
    const bf16* Bb = w1t + ((size_t)e * FF_ + n0) * D_;
    const bf16* gb0 = Bb + (size_t)sr0 * D_ + cs0;
    const bf16* gb1 = Bb + (size_t)sr1 * D_ + cs1;

    int ra_off[4], rb_off[4];
#pragma unroll
    for (int i = 0; i < 4; i++) {
        int r1 = wm * 64 + i * 16 + l15;
        ra_off[i] = r1 * 32 + (qd ^ ((r1 >> 1) & 3)) * 8;
        int r2 = wn * 64 + i * 16 + l15;
        rb_off[i] = r2 * 32 + (qd ^ ((r2 >> 1) & 3)) * 8;
    }

    f32x4 acc[4][4];
#pragma unroll
    for (int mt = 0; mt < 4; mt++)
#pragma unroll
        for (int nt = 0; nt < 4; nt++) acc[mt][nt] = (f32x4){0.f, 0.f, 0.f, 0.f};

    MOE_STAGE(As[0], Bs[0], 0);
    for (int k0 = 0; k0 < 960; k0 += 64) {
        MOE_STAGE(As[1], Bs[1], k0 + 32);
        MOE_STEP(As[0], Bs[0], "4");
        MOE_STAGE(As[0], Bs[0], k0 + 64);
        MOE_STEP(As[1], Bs[1], "4");
    }
    MOE_STAGE(As[1], Bs[1], 992);
    MOE_STEP(As[0], Bs[0], "4");
    MOE_STEP(As[1], Bs[1], "0");

    const float* b1e = b1 + (size_t)e * FF_;
#pragma unroll
    for (int mt = 0; mt < 4; mt++)
#pragma unroll
        for (int nt = 0; nt < 4; nt++) {
            int gn = n0 + wn * 64 + nt * 16 + l15;
            float bias = b1e[gn];
#pragma unroll
            for (int r = 0; r < 4; r++) {
                int gm = m0 + wm * 64 + mt * 16 + qd * 4 + r;
                act[(size_t)gm * FF_ + gn] = (bf16)gelu_f(acc[mt][nt][r] + bias);
            }
        }
}

// GEMM2: SPLIT-K=2. Grid (40, 8, 2) = 640 blocks (2.5/CU: kills the 320-on-256
// makespan quantization and restores wave-level TLP). Each block does K-half
// z*2048..+2048 (64 tiles), counted-vmcnt depth-2, then atomicAdd's its fp32
// partial into pre-zeroed y. Bias added by z==0 half only.
__global__ __launch_bounds__(256) void moe_gemm2_k(const bf16* __restrict__ act,
                                                   const bf16* __restrict__ w2t,
                                                   const float* __restrict__ b2,
                                                   const int* __restrict__ eoffp,
                                                   float* __restrict__ y) {
    int m0 = blockIdx.x * 128, n0 = blockIdx.y * 128;
    if (m0 >= eoffp[NE]) return;
    int e = 0;
#pragma unroll
    for (int i = 1; i < NE; i++) if (m0 >= eoffp[i]) e = i;
    int zk = blockIdx.z;
    int kbase = zk * 2048;

    __shared__ __align__(16) bf16 As[4][4096];
    __shared__ __align__(16) bf16 Bs[4][4096];
    int t = threadIdx.x;
    int wv = t >> 6, ln = t & 63;
    int wm = wv >> 1, wn = wv & 1, l15 = ln & 15, qd = ln >> 4;

    int sr0 = t >> 2, sr1 = 64 + sr0, cl = t & 3;
    int cs0 = (cl ^ ((sr0 >> 1) & 3)) * 8;
    int cs1 = (cl ^ ((sr1 >> 1) & 3)) * 8;
    const bf16* ga0 = act + (size_t)(m0 + sr0) * FF_ + kbase + cs0;
    const bf16* ga1 = act + (size_t)(m0 + sr1) * FF_ + kbase + cs1;
    const bf16* Bb = w2t + ((size_t)e * D_ + n0) * FF_;
    const bf16* gb0 = Bb + (size_t)sr0 * FF_ + kbase + cs0;
    const bf16* gb1 = Bb + (size_t)sr1 * FF_ + kbase + cs1;

    int ra_off[4], rb_off[4];
#pragma unroll
    for (int i = 0; i < 4; i++) {
        int r1 = wm * 64 + i * 16 + l15;
        ra_off[i] = r1 * 32 + (qd ^ ((r1 >> 1) & 3)) * 8;
        int r2 = wn * 64 + i * 16 + l15;
        rb_off[i] = r2 * 32 + (qd ^ ((r2 >> 1) & 3)) * 8;
    }

    f32x4 acc[4][4];
#pragma unroll
    for (int mt = 0; mt < 4; mt++)
#pragma unroll
        for (int nt = 0; nt < 4; nt++) acc[mt][nt] = (f32x4){0.f, 0.f, 0.f, 0.f};

    MOE_STAGE(As[0], Bs[0], 0);                 // tile 0
    MOE_STAGE(As[1], Bs[1], 32);                // tile 1; outstanding 8
    // main: computes tiles 0..59, stages through tile 61
    for (int k0 = 0; k0 < 1920; k0 += 128) {
        MOE_STAGE(As[2], Bs[2], k0 + 64);  MOE_STEP(As[0], Bs[0], "8");
        MOE_STAGE(As[3], Bs[3], k0 + 96);  MOE_STEP(As[1], Bs[1], "8");
        MOE_STAGE(As[0], Bs[0], k0 + 128); MOE_STEP(As[2], Bs[2], "8");
        MOE_STAGE(As[1], Bs[1], k0 + 160); MOE_STEP(As[3], Bs[3], "8");
    }
    // tail: tiles 60..63 (stage 62, 63)
    MOE_STAGE(As[2], Bs[2], 1984); MOE_STEP(As[0], Bs[0], "8");
    MOE_STAGE(As[3], Bs[3], 2016); MOE_STEP(As[1], Bs[1], "8");
    MOE_STEP(As[2], Bs[2], "4");
    MOE_STEP(As[3], Bs[3], "0");

    const float* b2e = b2 + (size_t)e * D_;
#pragma unroll
    for (int mt = 0; mt < 4; mt++)
#pragma unroll
        for (int nt = 0; nt < 4; nt++) {
            int gn = n0 + wn * 64 + nt * 16 + l15;
            float bias = (zk == 0) ? b2e[gn] : 0.0f;
#pragma unroll
            for (int r = 0; r < 4; r++) {
                int gm = m0 + wm * 64 + mt * 16 + qd * 4 + r;
                atomicAdd(&y[(size_t)gm * D_ + gn], acc[mt][nt][r] + bias);
            }
        }
}

// combine: out[tok] += g0*y[s0] + g1*y[s1]. One block per token.
__global__ __launch_bounds__(256) void combine_k(const float* __restrict__ y,
                                                 const int* __restrict__ sidx,
                                                 const float* __restrict__ tgate,
                                                 float* __restrict__ out) {
    int tok = blockIdx.x;
    int d = threadIdx.x * 4;
    int s0 = sidx[tok * 2], s1 = sidx[tok * 2 + 1];
    float g0 = tgate[tok * 2], g1 = tgate[tok * 2 + 1];
    float4 a = *(const float4*)(y + (size_t)s0 * D_ + d);
    float4 b = *(const float4*)(y + (size_t)s1 * D_ + d);
    float4 o = *(const float4*)(out + (size_t)tok * D_ + d);
    o.x += g0 * a.x + g1 * b.x;
    o.y += g0 * a.y + g1 * b.y;
    o.z += g0 * a.z + g1 * b.z;
    o.w += g0 * a.w + g1 * b.w;
    *(float4*)(out + (size_t)tok * D_ + d) = o;
}

// ---------------------------------------------------------------------------
extern "C" void kernel_launch(void* const* d_in, const int* in_sizes, int n_in,
                              void* d_out, int out_size, void* d_ws, size_t ws_size,
                              hipStream_t stream) {
    const float* x   = (const float*)d_in[0];
    const float* anw = (const float*)d_in[1];
    const float* wq  = (const float*)d_in[2];
    const float* wk  = (const float*)d_in[3];
    const float* wv  = (const float*)d_in[4];
    const float* wo  = (const float*)d_in[5];
    const float* mnw = (const float*)d_in[6];
    const float* rw  = (const float*)d_in[7];
    const float* w1  = (const float*)d_in[8];
    const float* b1  = (const float*)d_in[9];
    const float* w2  = (const float*)d_in[10];
    const float* b2  = (const float*)d_in[11];
    float* out = (float*)d_out;

    char* p = (char*)d_ws;
    auto take = [&](size_t n) { char* r = p; p += (n + 255) & ~(size_t)255; return r; };
    bf16* h1h = (bf16*)take((size_t)OUTN * 2);
    bf16* h1l = (bf16*)take((size_t)OUTN * 2);
    bf16* qh  = (bf16*)take((size_t)OUTN * 2);
    bf16* ql  = (bf16*)take((size_t)OUTN * 2);
    bf16* kh  = (bf16*)take((size_t)OUTN * 2);
    bf16* kl  = (bf16*)take((size_t)OUTN * 2);
    bf16* vh  = (bf16*)take((size_t)OUTN * 2);
    bf16* vl  = (bf16*)take((size_t)OUTN * 2);
    bf16* wqth = (bf16*)take((size_t)D_ * D_ * 2);
    bf16* wqtl = (bf16*)take((size_t)D_ * D_ * 2);
    bf16* wkth = (bf16*)take((size_t)D_ * D_ * 2);
    bf16* wktl = (bf16*)take((size_t)D_ * D_ * 2);
    bf16* wvth = (bf16*)take((size_t)D_ * D_ * 2);
    bf16* wvtl = (bf16*)take((size_t)D_ * D_ * 2);
    bf16* woth = (bf16*)take((size_t)D_ * D_ * 2);
    bf16* wotl = (bf16*)take((size_t)D_ * D_ * 2);
    bf16* w1t = (bf16*)take((size_t)NE * FF_ * D_ * 2);
    bf16* w2t = (bf16*)take((size_t)NE * FF_ * D_ * 2);
    bf16* act = (bf16*)take((size_t)CAP * FF_ * 2);
    int*   tidx  = (int*)take(NTOK * 2 * 4);
    float* tgate = (float*)take(NTOK * 2 * 4);
    int*   sidx  = (int*)take(NTOK * 2 * 4);
    int*   ecnt  = (int*)take(64);
    int*   ecnt2 = (int*)take(64);
    float* psum  = (float*)take(64);
    int*   eoffp = (int*)take(64);
    int*   stok  = (int*)take(CAP * 4);

    // aliases over dead buffers:
    bf16*  aoh = h1h;            // h1 dead after QKV gemm
    bf16*  aol = h1l;
    float* h_f = (float*)qh;     // q dead after attention (spans qh+ql, 8 MB)
    bf16*  h_b = kh;             // k dead after attention
    float* y   = (float*)vh;     // v + attn weight splits dead after WO: 8+16=24 MB >= CAP*D*4=21 MB

    hipMemsetAsync(ecnt, 0, NE * 4, stream);
    hipMemsetAsync(psum, 0, NE * 4, stream);
    hipMemsetAsync(stok, 0, CAP * 4, stream);

    // weight transposes
    trans_split_k<<<dim3(32, 32, 4), 256, 0, stream>>>(wq, wk, wv, wo,
        wqth, wqtl, wkth, wktl, wvth, wvtl, woth, wotl);
    transpose_cast4_k<<<dim3(FF_ / 64, D_ / 64, NE), 256, 0, stream>>>(w1, w1t, D_, FF_);
    transpose_cast4_k<<<dim3(D_ / 64, FF_ / 64, NE), 256, 0, stream>>>(w2, w2t, FF_, D_);

    // attention path (split-bf16 MFMA, fp32 fidelity for router)
    rmsnorm_k<<<NTOK, 256, 0, stream>>>(x, anw, nullptr, h1h, h1l);
    gemm_qkv_k<<<dim3(16, 24), 256, 0, stream>>>(h1h, h1l,
        wqth, wqtl, wkth, wktl, wvth, wvtl, qh, ql, kh, kl, vh, vl);
    attn_mfma_k<<<dim3(16, 16, 2), 256, 0, stream>>>(qh, ql, kh, kl, vh, vl, aoh, aol);
    gemm_wo_k<<<dim3(16, 8), 256, 0, stream>>>(aoh, aol, woth, wotl, out, x);

    // MoE (y zeroed after attention path frees its alias space)
    hipMemsetAsync(y, 0, (size_t)CAP * D_ * 4, stream);
    rmsnorm_k<<<NTOK, 256, 0, stream>>>(out, mnw, h_f, h_b, nullptr);
    router_k<<<NTOK / 4, 256, 0, stream>>>(h_f, rw, tidx, tgate, ecnt, psum);
    passb_k<<<1, 64, 0, stream>>>(ecnt, psum, eoffp, ecnt2, out + OUTN);
    scatter_k<<<NTOK / 256, 256, 0, stream>>>(tidx, eoffp, ecnt2, stok, sidx);
    moe_gemm1_k<<<dim3(CAP / 128, FF_ / 128), 256, 0, stream>>>(h_b, w1t, b1, eoffp, stok, act);
    moe_gemm2_k<<<dim3(CAP / 128, D_ / 128, 2), 256, 0, stream>>>(act, w2t, b2, eoffp, y);
    combine_k<<<NTOK, 256, 0, stream>>>(y, sidx, tgate, out);
}

// Round 6
// 776.092 us; speedup vs baseline: 1.0253x; 1.0253x over previous
//
#include <hip/hip_runtime.h>

typedef __bf16 bf16;
typedef __bf16 bf16x4 __attribute__((ext_vector_type(4)));
typedef __bf16 bf16x8 __attribute__((ext_vector_type(8)));
typedef float f32x4 __attribute__((ext_vector_type(4)));

#define D_   1024
#define S_   1024
#define B_   2
#define NTOK 2048
#define FF_  4096
#define NE   8
#define CAP  5120
#define OUTN 2097152

// fast tanh-form GELU: one v_exp_f32 instead of libm tanhf.
__device__ __forceinline__ float gelu_f(float x) {
    float u = 0.7978845608028654f * (x + 0.044715f * x * x * x);
    float a = fabsf(u);
    float e = __expf(-2.0f * a);
    float t = (1.0f - e) / (1.0f + e);
    t = copysignf(t, u);
    return 0.5f * x * (1.0f + t);
}

// async global->LDS, 16B per lane. LDS dest must be wave-uniform base; HW adds lane*16.
__device__ __forceinline__ void gload16(const void* g, void* l) {
    __builtin_amdgcn_global_load_lds((const __attribute__((address_space(1))) unsigned int*)g,
                                     (__attribute__((address_space(3))) unsigned int*)l,
                                     16, 0, 0);
}

// counted vmem wait (T4): keep N loads in flight across the barrier.
#define VMCNT(n) asm volatile("s_waitcnt vmcnt(" n ")" ::: "memory")
// raw barrier with compiler-level memory fences (no vmcnt(0) drain).
#define BARRIER() do { asm volatile("" ::: "memory"); \
                       __builtin_amdgcn_s_barrier();  \
                       asm volatile("" ::: "memory"); } while (0)

// ---------------------------------------------------------------------------
// RMSNorm: one block per row of 1024. Optional fp32 / bf16-hi / bf16-lo outs.
// ---------------------------------------------------------------------------
__global__ __launch_bounds__(256) void rmsnorm_k(const float* __restrict__ x,
                                                 const float* __restrict__ w,
                                                 float* __restrict__ yf,
                                                 bf16* __restrict__ yhi,
                                                 bf16* __restrict__ ylo) {
    int row = blockIdx.x;
    int t = threadIdx.x;
    const float* xr = x + (size_t)row * D_;
    float4 v = *(const float4*)(xr + t * 4);
    float ss = v.x * v.x + v.y * v.y + v.z * v.z + v.w * v.w;
    for (int off = 32; off; off >>= 1) ss += __shfl_down(ss, off);
    __shared__ float wsum[4];
    if ((t & 63) == 0) wsum[t >> 6] = ss;
    __syncthreads();
    float tot = wsum[0] + wsum[1] + wsum[2] + wsum[3];
    float rr = rsqrtf(tot * (1.0f / D_) + 1e-6f);
    float4 wv = *(const float4*)(w + t * 4);
    float y[4];
    y[0] = v.x * rr * wv.x; y[1] = v.y * rr * wv.y;
    y[2] = v.z * rr * wv.z; y[3] = v.w * rr * wv.w;
    if (yf) *(float4*)(yf + (size_t)row * D_ + t * 4) = *(float4*)y;
    if (yhi) {
#pragma unroll
        for (int i = 0; i < 4; i++) {
            bf16 hi = (bf16)y[i];
            yhi[(size_t)row * D_ + t * 4 + i] = hi;
            if (ylo) ylo[(size_t)row * D_ + t * 4 + i] = (bf16)(y[i] - (float)hi);
        }
    }
}

// ---------------------------------------------------------------------------
// Transpose + split-cast fp32 [1024][1024] -> bf16 hi/lo [N][K]. (attn weights)
// ---------------------------------------------------------------------------
__global__ __launch_bounds__(256) void trans_split_k(
    const float* __restrict__ w0, const float* __restrict__ w1p,
    const float* __restrict__ w2p, const float* __restrict__ w3,
    bf16* o0h, bf16* o0l, bf16* o1h, bf16* o1l,
    bf16* o2h, bf16* o2l, bf16* o3h, bf16* o3l) {
    int z = blockIdx.z;
    const float* src = (z == 0) ? w0 : (z == 1) ? w1p : (z == 2) ? w2p : w3;
    bf16* dh = (z == 0) ? o0h : (z == 1) ? o1h : (z == 2) ? o2h : o3h;
    bf16* dl = (z == 0) ? o0l : (z == 1) ? o1l : (z == 2) ? o2l : o3l;
    __shared__ float tl[32][33];
    int c0 = blockIdx.x * 32, r0 = blockIdx.y * 32;
    int tx = threadIdx.x & 31, ty = threadIdx.x >> 5;
#pragma unroll
    for (int i = 0; i < 4; i++) {
        int r = ty + i * 8;
        tl[r][tx] = src[(size_t)(r0 + r) * 1024 + c0 + tx];
    }
    __syncthreads();
#pragma unroll
    for (int i = 0; i < 4; i++) {
        int c = ty + i * 8;
        float v = tl[tx][c];
        bf16 hi = (bf16)v;
        dh[(size_t)(c0 + c) * 1024 + r0 + tx] = hi;
        dl[(size_t)(c0 + c) * 1024 + r0 + tx] = (bf16)(v - (float)hi);
    }
}

// ---------------------------------------------------------------------------
// Vectorized transpose + cast fp32 -> bf16: in [z][R][C] -> out [z][C][R].
// 64x64 tile, float4 loads (16B/lane), bf16x4 stores (8B/lane).  (MoE weights)
// ---------------------------------------------------------------------------
__global__ __launch_bounds__(256) void transpose_cast4_k(const float* __restrict__ in,
                                                         bf16* __restrict__ out,
                                                         int R, int C) {
    __shared__ float tl[64][65];
    size_t base = (size_t)blockIdx.z * R * C;
    const float* src = in + base;
    bf16* dst = out + base;
    int c0 = blockIdx.x * 64, r0 = blockIdx.y * 64;
    int t = threadIdx.x;
    int lr = t >> 4;            // 0..15
    int lc = (t & 15) * 4;      // 0,4,..,60
#pragma unroll
    for (int i = 0; i < 4; i++) {
        int r = lr + i * 16;
        float4 v = *(const float4*)(src + (size_t)(r0 + r) * C + c0 + lc);
        tl[r][lc] = v.x; tl[r][lc + 1] = v.y; tl[r][lc + 2] = v.z; tl[r][lc + 3] = v.w;
    }
    __syncthreads();
    int wc = t >> 4;            // col 0..15 (+16*i)
    int wr = (t & 15) * 4;      // row chunk 0,4,..,60
#pragma unroll
    for (int i = 0; i < 4; i++) {
        int c = wc + i * 16;
        bf16x4 o;
        o[0] = (bf16)tl[wr][c];     o[1] = (bf16)tl[wr + 1][c];
        o[2] = (bf16)tl[wr + 2][c]; o[3] = (bf16)tl[wr + 3][c];
        *(bf16x4*)(dst + (size_t)(c0 + c) * R + r0 + wr) = o;
    }
}

// ---------------------------------------------------------------------------
// Split-bf16 dense GEMM, 128x128 tile, BK=32, 4 waves 2x2.
// A hi/lo [M][K=1024], B hi/lo [N][K=1024]. global_load_lds + XOR swizzle +
// T4 counted-vmcnt pipeline (stage next tile BEFORE compute; vmcnt(8) keeps
// the prefetch in flight across raw barriers). 3-product Markidis MFMA.
// ---------------------------------------------------------------------------
#define SPLIT_STAGE(bi, k0)                             \
    gload16(gah0 + (k0), Lah[bi] + wv * 512);           \
    gload16(gah1 + (k0), Lah[bi] + 2048 + wv * 512);    \
    gload16(gal0 + (k0), Lal[bi] + wv * 512);           \
    gload16(gal1 + (k0), Lal[bi] + 2048 + wv * 512);    \
    gload16(gbh0 + (k0), Lbh[bi] + wv * 512);           \
    gload16(gbh1 + (k0), Lbh[bi] + 2048 + wv * 512);    \
    gload16(gbl0 + (k0), Lbl[bi] + wv * 512);           \
    gload16(gbl1 + (k0), Lbl[bi] + 2048 + wv * 512);

#define SPLIT_COMPUTE(bi) {                                                            \
    bf16x8 fah[4], fal[4], fbh[4], fbl[4];                                             \
    _Pragma("unroll") for (int i = 0; i < 4; i++) {                                    \
        fah[i] = *(const bf16x8*)(Lah[bi] + ra_off[i]);                                \
        fal[i] = *(const bf16x8*)(Lal[bi] + ra_off[i]);                                \
        fbh[i] = *(const bf16x8*)(Lbh[bi] + rb_off[i]);                                \
        fbl[i] = *(const bf16x8*)(Lbl[bi] + rb_off[i]);                                \
    }                                                                                  \
    _Pragma("unroll") for (int mt = 0; mt < 4; mt++)                                   \
    _Pragma("unroll") for (int nt = 0; nt < 4; nt++) {                                 \
        acc[mt][nt] = __builtin_amdgcn_mfma_f32_16x16x32_bf16(fah[mt], fbh[nt], acc[mt][nt], 0, 0, 0); \
        acc[mt][nt] = __builtin_amdgcn_mfma_f32_16x16x32_bf16(fah[mt], fbl[nt], acc[mt][nt], 0, 0, 0); \
        acc[mt][nt] = __builtin_amdgcn_mfma_f32_16x16x32_bf16(fal[mt], fbh[nt], acc[mt][nt], 0, 0, 0); \
    } }

#define SPLIT_STEP(bi, VM)          \
    VMCNT(VM);                      \
    BARRIER();                      \
    SPLIT_COMPUTE(bi);              \
    BARRIER();

// declarations + pointers (KOFF = K start offset for split-K slices)
#define SPLIT_DECLS(KOFF)                                                              \
    __shared__ __align__(16) bf16 Lah[2][4096];                                        \
    __shared__ __align__(16) bf16 Lal[2][4096];                                        \
    __shared__ __align__(16) bf16 Lbh[2][4096];                                        \
    __shared__ __align__(16) bf16 Lbl[2][4096];                                        \
    int t = threadIdx.x;                                                               \
    int wv = t >> 6, ln = t & 63;                                                      \
    int wm = wv >> 1, wn = wv & 1, l15 = ln & 15, qd = ln >> 4;                        \
    int sr0 = t >> 2, sr1 = 64 + sr0, cl = t & 3;                                      \
    int cs0 = (cl ^ ((sr0 >> 1) & 3)) * 8;                                             \
    int cs1 = (cl ^ ((sr1 >> 1) & 3)) * 8;                                             \
    const bf16* gah0 = Ah + (size_t)(m0 + sr0) * 1024 + (KOFF) + cs0;                  \
    const bf16* gah1 = Ah + (size_t)(m0 + sr1) * 1024 + (KOFF) + cs1;                  \
    const bf16* gal0 = Al + (size_t)(m0 + sr0) * 1024 + (KOFF) + cs0;                  \
    const bf16* gal1 = Al + (size_t)(m0 + sr1) * 1024 + (KOFF) + cs1;                  \
    const bf16* gbh0 = Bh + (size_t)(n0 + sr0) * 1024 + (KOFF) + cs0;                  \
    const bf16* gbh1 = Bh + (size_t)(n0 + sr1) * 1024 + (KOFF) + cs1;                  \
    const bf16* gbl0 = Bl + (size_t)(n0 + sr0) * 1024 + (KOFF) + cs0;                  \
    const bf16* gbl1 = Bl + (size_t)(n0 + sr1) * 1024 + (KOFF) + cs1;                  \
    int ra_off[4], rb_off[4];                                                          \
    _Pragma("unroll") for (int i = 0; i < 4; i++) {                                    \
        int r1 = wm * 64 + i * 16 + l15;                                               \
        ra_off[i] = r1 * 32 + (qd ^ ((r1 >> 1) & 3)) * 8;                              \
        int r2 = wn * 64 + i * 16 + l15;                                               \
        rb_off[i] = r2 * 32 + (qd ^ ((r2 >> 1) & 3)) * 8;                              \
    }                                                                                  \
    f32x4 acc[4][4];                                                                   \
    _Pragma("unroll") for (int mt = 0; mt < 4; mt++)                                   \
    _Pragma("unroll") for (int nt = 0; nt < 4; nt++) acc[mt][nt] = (f32x4){0.f,0.f,0.f,0.f};

// QKV: grid (16, 24): y = weight*8 + n-tile. K=1024 (32 tiles). Outputs hi/lo.
__global__ __launch_bounds__(256) void gemm_qkv_k(
    const bf16* __restrict__ Ah, const bf16* __restrict__ Al,
    const bf16* __restrict__ Bqh, const bf16* __restrict__ Bql,
    const bf16* __restrict__ Bkh, const bf16* __restrict__ Bkl,
    const bf16* __restrict__ Bvh, const bf16* __restrict__ Bvl,
    bf16* Cqh, bf16* Cql, bf16* Ckh, bf16* Ckl, bf16* Cvh, bf16* Cvl) {
    int gy = blockIdx.y, zw = gy >> 3;
    const bf16* Bh = (zw == 0) ? Bqh : (zw == 1) ? Bkh : Bvh;
    const bf16* Bl = (zw == 0) ? Bql : (zw == 1) ? Bkl : Bvl;
    bf16* Ch = (zw == 0) ? Cqh : (zw == 1) ? Ckh : Cvh;
    bf16* Cl = (zw == 0) ? Cql : (zw == 1) ? Ckl : Cvl;
    int m0 = blockIdx.x * 128, n0 = (gy & 7) * 128;
    SPLIT_DECLS(0)
    SPLIT_STAGE(0, 0);
    for (int k0 = 0; k0 < 960; k0 += 64) {
        SPLIT_STAGE(1, k0 + 32);
        SPLIT_STEP(0, "8");
        SPLIT_STAGE(0, k0 + 64);
        SPLIT_STEP(1, "8");
    }
    SPLIT_STAGE(1, 992);
    SPLIT_STEP(0, "8");
    SPLIT_STEP(1, "0");
#pragma unroll
    for (int mt = 0; mt < 4; mt++)
#pragma unroll
        for (int nt = 0; nt < 4; nt++)
#pragma unroll
            for (int r = 0; r < 4; r++) {
                int gm = m0 + wm * 64 + mt * 16 + qd * 4 + r;
                int gn = n0 + wn * 64 + nt * 16 + l15;
                float vv = acc[mt][nt][r];
                bf16 hi = (bf16)vv;
                Ch[(size_t)gm * D_ + gn] = hi;
                Cl[(size_t)gm * D_ + gn] = (bf16)(vv - (float)hi);
            }
}

// WO: grid (16, 8, 4) SPLIT-K=4 (512 blocks = 2/CU; was 128 = 0.5/CU).
// Each z does K-slice of 256 (8 tiles). C pre-filled with X; partials
// accumulated with fp32 atomicAdd (4 distinct adds per element).
__global__ __launch_bounds__(256) void gemm_wo_k(
    const bf16* __restrict__ Ah, const bf16* __restrict__ Al,
    const bf16* __restrict__ Bh, const bf16* __restrict__ Bl,
    float* __restrict__ C) {
    int m0 = blockIdx.x * 128, n0 = blockIdx.y * 128;
    int kb = blockIdx.z * 256;
    SPLIT_DECLS(kb)
    SPLIT_STAGE(0, 0);
    for (int k0 = 0; k0 < 192; k0 += 64) {
        SPLIT_STAGE(1, k0 + 32);
        SPLIT_STEP(0, "8");
        SPLIT_STAGE(0, k0 + 64);
        SPLIT_STEP(1, "8");
    }
    SPLIT_STAGE(1, 224);
    SPLIT_STEP(0, "8");
    SPLIT_STEP(1, "0");
#pragma unroll
    for (int mt = 0; mt < 4; mt++)
#pragma unroll
        for (int nt = 0; nt < 4; nt++)
#pragma unroll
            for (int r = 0; r < 4; r++) {
                int gm = m0 + wm * 64 + mt * 16 + qd * 4 + r;
                int gn = n0 + wn * 64 + nt * 16 + l15;
                atomicAdd(&C[(size_t)gm * D_ + gn], acc[mt][nt][r]);
            }
}

// ---------------------------------------------------------------------------
// Split-bf16 MFMA flash attention. Block = (qt desc, h, b): 64 q-rows, 4 waves.
// ---------------------------------------------------------------------------
#define AP 72

__global__ __launch_bounds__(256) void attn_mfma_k(
    const bf16* __restrict__ qhp, const bf16* __restrict__ qlp,
    const bf16* __restrict__ khp, const bf16* __restrict__ klp,
    const bf16* __restrict__ vhp, const bf16* __restrict__ vlp,
    bf16* __restrict__ aoh, bf16* __restrict__ aol) {
    int qt = (int)gridDim.x - 1 - (int)blockIdx.x;  // deep tiles first
    int h = blockIdx.y, b = blockIdx.z;
    __shared__ bf16 Ksh[64 * AP], Ksl[64 * AP], VTh[64 * AP], VTl[64 * AP];
    __shared__ bf16 Ph[4][16 * AP], Pl[4][16 * AP];
    int t = threadIdx.x, wv = t >> 6, ln = t & 63, l15 = ln & 15, qd = ln >> 4;

    bf16x8 aqh[2], aql[2];
    {
        size_t qb = ((size_t)(b * S_ + qt * 64 + wv * 16 + l15)) * D_ + h * 64 + qd * 8;
        aqh[0] = *(const bf16x8*)(qhp + qb);
        aqh[1] = *(const bf16x8*)(qhp + qb + 32);
        aql[0] = *(const bf16x8*)(qlp + qb);
        aql[1] = *(const bf16x8*)(qlp + qb + 32);
    }
    f32x4 oacc[4];
    float mrow[4], lrow[4];
#pragma unroll
    for (int i = 0; i < 4; i++) {
        oacc[i] = (f32x4){0.f, 0.f, 0.f, 0.f};
        mrow[i] = -1e30f; lrow[i] = 0.0f;
    }

    for (int kt = 0; kt <= qt; kt++) {
        __syncthreads();
#pragma unroll
        for (int j = 0; j < 2; j++) {
            int idx = t + j * 256;
            int row = idx >> 3, ch = (idx & 7) * 8;
            size_t g = ((size_t)(b * S_ + kt * 64 + row)) * D_ + h * 64 + ch;
            *(bf16x8*)&Ksh[row * AP + ch] = *(const bf16x8*)(khp + g);
            *(bf16x8*)&Ksl[row * AP + ch] = *(const bf16x8*)(klp + g);
            bf16x8 vvh = *(const bf16x8*)(vhp + g);
            bf16x8 vvl = *(const bf16x8*)(vlp + g);
#pragma unroll
            for (int jj = 0; jj < 8; jj++) {
                VTh[(ch + jj) * AP + row] = vvh[jj];
                VTl[(ch + jj) * AP + row] = vvl[jj];
            }
        }
        __syncthreads();

        f32x4 sacc[4];
#pragma unroll
        for (int nt = 0; nt < 4; nt++) sacc[nt] = (f32x4){0.f, 0.f, 0.f, 0.f};
#pragma unroll
        for (int ks = 0; ks < 2; ks++) {
#pragma unroll
            for (int nt = 0; nt < 4; nt++) {
                bf16x8 bh = *(const bf16x8*)&Ksh[(nt * 16 + l15) * AP + ks * 32 + qd * 8];
                bf16x8 bl = *(const bf16x8*)&Ksl[(nt * 16 + l15) * AP + ks * 32 + qd * 8];
                sacc[nt] = __builtin_amdgcn_mfma_f32_16x16x32_bf16(aqh[ks], bh, sacc[nt], 0, 0, 0);
                sacc[nt] = __builtin_amdgcn_mfma_f32_16x16x32_bf16(aqh[ks], bl, sacc[nt], 0, 0, 0);
                sacc[nt] = __builtin_amdgcn_mfma_f32_16x16x32_bf16(aql[ks], bh, sacc[nt], 0, 0, 0);
            }
        }
        bool diag = (kt == qt);
#pragma unroll
        for (int r = 0; r < 4; r++) {
            float s0[4];
#pragma unroll
            for (int nt = 0; nt < 4; nt++) {
                s0[nt] = sacc[nt][r] * 0.125f;
                if (diag && (nt * 16 + l15) > (wv * 16 + qd * 4 + r)) s0[nt] = -1e30f;
            }
            float vmax = fmaxf(fmaxf(s0[0], s0[1]), fmaxf(s0[2], s0[3]));
            for (int off = 1; off < 16; off <<= 1) vmax = fmaxf(vmax, __shfl_xor(vmax, off));
            float mnew = fmaxf(mrow[r], vmax);
            float alpha = __expf(mrow[r] - mnew);
            float p[4], rs = 0.0f;
#pragma unroll
            for (int nt = 0; nt < 4; nt++) { p[nt] = __expf(s0[nt] - mnew); rs += p[nt]; }
            for (int off = 1; off < 16; off <<= 1) rs += __shfl_xor(rs, off);
            lrow[r] = lrow[r] * alpha + rs;
            mrow[r] = mnew;
#pragma unroll
            for (int nt = 0; nt < 4; nt++) oacc[nt][r] *= alpha;
            int prow = qd * 4 + r;
#pragma unroll
            for (int nt = 0; nt < 4; nt++) {
                bf16 hi = (bf16)p[nt];
                Ph[wv][prow * AP + nt * 16 + l15] = hi;
                Pl[wv][prow * AP + nt * 16 + l15] = (bf16)(p[nt] - (float)hi);
            }
        }
        // PV: same-wave LDS RAW (in-order DS pipe), no barrier needed.
#pragma unroll
        for (int ks2 = 0; ks2 < 2; ks2++) {
            bf16x8 aph = *(const bf16x8*)&Ph[wv][l15 * AP + ks2 * 32 + qd * 8];
            bf16x8 apl = *(const bf16x8*)&Pl[wv][l15 * AP + ks2 * 32 + qd * 8];
#pragma unroll
            for (int nt = 0; nt < 4; nt++) {
                bf16x8 bvh = *(const bf16x8*)&VTh[(nt * 16 + l15) * AP + ks2 * 32 + qd * 8];
                bf16x8 bvl = *(const bf16x8*)&VTl[(nt * 16 + l15) * AP + ks2 * 32 + qd * 8];
                oacc[nt] = __builtin_amdgcn_mfma_f32_16x16x32_bf16(aph, bvh, oacc[nt], 0, 0, 0);
                oacc[nt] = __builtin_amdgcn_mfma_f32_16x16x32_bf16(aph, bvl, oacc[nt], 0, 0, 0);
                oacc[nt] = __builtin_amdgcn_mfma_f32_16x16x32_bf16(apl, bvh, oacc[nt], 0, 0, 0);
            }
        }
    }

#pragma unroll
    for (int r = 0; r < 4; r++) {
        float inv = 1.0f / lrow[r];
        size_t rowa = ((size_t)(b * S_ + qt * 64 + wv * 16 + qd * 4 + r)) * D_ + h * 64;
#pragma unroll
        for (int nt = 0; nt < 4; nt++) {
            float o = oacc[nt][r] * inv;
            bf16 hi = (bf16)o;
            aoh[rowa + nt * 16 + l15] = hi;
            aol[rowa + nt * 16 + l15] = (bf16)(o - (float)hi);
        }
    }
}

// ---------------------------------------------------------------------------
// Router: 4 tokens/block (wave each). fp32 logits -> softmax -> top2.
// ---------------------------------------------------------------------------
__global__ __launch_bounds__(256) void router_k(const float* __restrict__ h,
                                                const float* __restrict__ rw,
                                                int* __restrict__ tidx,
                                                float* __restrict__ tgate,
                                                int* __restrict__ ecnt,
                                                float* __restrict__ psum) {
    int wv = threadIdx.x >> 6, ln = threadIdx.x & 63;
    int tok = blockIdx.x * 4 + wv;
    const float* hr = h + (size_t)tok * D_;
    float acc[NE];
#pragma unroll
    for (int e = 0; e < NE; e++) acc[e] = 0.0f;
    int base = ln * 16;
#pragma unroll
    for (int c = 0; c < 4; c++) {
        float4 hv = *(const float4*)(hr + base + c * 4);
        const float* rp = rw + (size_t)(base + c * 4) * NE;
        float hx[4] = {hv.x, hv.y, hv.z, hv.w};
#pragma unroll
        for (int jj = 0; jj < 4; jj++)
#pragma unroll
            for (int e = 0; e < NE; e++)
                acc[e] = fmaf(hx[jj], rp[jj * NE + e], acc[e]);
    }
#pragma unroll
    for (int e = 0; e < NE; e++)
        for (int off = 32; off; off >>= 1) acc[e] += __shfl_down(acc[e], off);

    __shared__ float pb[4][NE];
    if (ln == 0) {
        float mx = acc[0];
#pragma unroll
        for (int e = 1; e < NE; e++) mx = fmaxf(mx, acc[e]);
        float p[NE], ssum = 0.0f;
#pragma unroll
        for (int e = 0; e < NE; e++) { p[e] = expf(acc[e] - mx); ssum += p[e]; }
        float inv = 1.0f / ssum;
#pragma unroll
        for (int e = 0; e < NE; e++) p[e] *= inv;
        int i0 = 0; float b0 = p[0];
#pragma unroll
        for (int e = 1; e < NE; e++) if (p[e] > b0) { b0 = p[e]; i0 = e; }
        int i1 = -1; float b1v = -1.0f;
#pragma unroll
        for (int e = 0; e < NE; e++) if (e != i0 && p[e] > b1v) { b1v = p[e]; i1 = e; }
        tidx[tok * 2] = i0; tidx[tok * 2 + 1] = i1;
        tgate[tok * 2] = b0; tgate[tok * 2 + 1] = b1v;
        atomicAdd(&ecnt[i0], 1);
        atomicAdd(&ecnt[i1], 1);
#pragma unroll
        for (int e = 0; e < NE; e++) pb[wv][e] = p[e];
    }
    __syncthreads();
    if (threadIdx.x < NE) {
        float s2 = pb[0][threadIdx.x] + pb[1][threadIdx.x] + pb[2][threadIdx.x] + pb[3][threadIdx.x];
        atomicAdd(&psum[threadIdx.x], s2);
    }
}

__global__ void passb_k(const int* __restrict__ ecnt, const float* __restrict__ psum,
                        int* __restrict__ eoffp, int* __restrict__ ecnt2,
                        float* __restrict__ out_tail) {
    if (threadIdx.x == 0) {
        int off = 0; float loss = 0.0f;
        for (int e = 0; e < NE; e++) {
            eoffp[e] = off;
            int c = ecnt[e];
            off += (c + 127) & ~127;
            loss += (c * (1.0f / 4096.0f)) * (psum[e] * (1.0f / 2048.0f));
            out_tail[1 + e] = (float)c;
            ecnt2[e] = 0;
        }
        eoffp[NE] = off;
        out_tail[0] = 8.0f * loss;
    }
}

// scatter: slot list per expert + inverse map (slot of each (tok,k)).
__global__ __launch_bounds__(256) void scatter_k(const int* __restrict__ tidx,
                                                 const int* __restrict__ eoffp,
                                                 int* __restrict__ ecnt2,
                                                 int* __restrict__ stok,
                                                 int* __restrict__ sidx) {
    int tok = blockIdx.x * 256 + threadIdx.x;
    for (int k = 0; k < 2; k++) {
        int e = tidx[tok * 2 + k];
        int pos = eoffp[e] + atomicAdd(&ecnt2[e], 1);
        stok[pos] = tok;
        sidx[tok * 2 + k] = pos;
    }
}

// ---------------------------------------------------------------------------
// MoE GEMMs with T4 counted-vmcnt pipelining. Both-sides XOR swizzle; linear LDS.
// ---------------------------------------------------------------------------
#define MOE_STAGE(bufA, bufB, k0)                       \
    gload16(ga0 + (k0), (bufA) + wv * 512);             \
    gload16(ga1 + (k0), (bufA) + 2048 + wv * 512);      \
    gload16(gb0 + (k0), (bufB) + wv * 512);             \
    gload16(gb1 + (k0), (bufB) + 2048 + wv * 512);

#define MOE_TILE(bufA, bufB) {                                                         \
    bf16x8 af[4], bfr[4];                                                              \
    _Pragma("unroll") for (int i = 0; i < 4; i++) {                                    \
        af[i]  = *(const bf16x8*)((bufA) + ra_off[i]);                                 \
        bfr[i] = *(const bf16x8*)((bufB) + rb_off[i]);                                 \
    }                                                                                  \
    _Pragma("unroll") for (int mt = 0; mt < 4; mt++)                                   \
    _Pragma("unroll") for (int nt = 0; nt < 4; nt++)                                   \
        acc[mt][nt] = __builtin_amdgcn_mfma_f32_16x16x32_bf16(af[mt], bfr[nt], acc[mt][nt], 0, 0, 0); }

#define MOE_STEP(rdA, rdB, VM)      \
    VMCNT(VM);                      \
    BARRIER();                      \
    MOE_TILE(rdA, rdB);             \
    BARRIER();

// GEMM1: K=1024 (32 tiles), 2 buffers depth-1. Grid (40,32)=1280 blocks (5/CU).
__global__ __launch_bounds__(256) void moe_gemm1_k(const bf16* __restrict__ hB,
                                                   const bf16* __restrict__ w1t,
                                                   const float* __restrict__ b1,
                                                   const int* __restrict__ eoffp,
                                                   const int* __restrict__ stok,
                                                   bf16* __restrict__ act) {
    int m0 = blockIdx.x * 128, n0 = blockIdx.y * 128;
    if (m0 >= eoffp[NE]) return;
    int e = 0;
#pragma unroll
    for (int i = 1; i < NE; i++) if (m0 >= eoffp[i]) e = i;

    __shared__ __align__(16) bf16 As[2][4096];
    __shared__ __align__(16) bf16 Bs[2][4096];
    int t = threadIdx.x;
    int wv = t >> 6, ln = t & 63;
    int wm = wv >> 1, wn = wv & 1, l15 = ln & 15, qd = ln >> 4;

    int sr0 = t >> 2, sr1 = 64 + sr0, cl = t & 3;
    int cs0 = (cl ^ ((sr0 >> 1) & 3)) * 8;
    int cs1 = (cl ^ ((sr1 >> 1) & 3)) * 8;
    const bf16* ga0 = hB + (size_t)stok[m0 + sr0] * D_ + cs0;
    const bf16* ga1 = hB + (size_t)stok[m0 + sr1] * D_ + cs1;
    const bf16* Bb = w1t + ((size_t)e * FF_ + n0) * D_;
    const bf16* gb0 = Bb + (size_t)sr0 * D_ + cs0;
    const bf16* gb1 = Bb + (size_t)sr1 * D_ + cs1;

    int ra_off[4], rb_off[4];
#pragma unroll
    for (int i = 0; i < 4; i++) {
        int r1 = wm * 64 + i * 16 + l15;
        ra_off[i] = r1 * 32 + (qd ^ ((r1 >> 1) & 3)) * 8;
        int r2 = wn * 64 + i * 16 + l15;
        rb_off[i] = r2 * 32 + (qd ^ ((r2 >> 1) & 3)) * 8;
    }

    f32x4 acc[4][4];
#pragma unroll
    for (int mt = 0; mt < 4; mt++)
#pragma unroll
        for (int nt = 0; nt < 4; nt++) acc[mt][nt] = (f32x4){0.f, 0.f, 0.f, 0.f};

    MOE_STAGE(As[0], Bs[0], 0);
    for (int k0 = 0; k0 < 960; k0 += 64) {
        MOE_STAGE(As[1], Bs[1], k0 + 32);
        MOE_STEP(As[0], Bs[0], "4");
        MOE_STAGE(As[0], Bs[0], k0 + 64);
        MOE_STEP(As[1], Bs[1], "4");
    }
    MOE_STAGE(As[1], Bs[1], 992);
    MOE_STEP(As[0], Bs[0], "4");
    MOE_STEP(As[1], Bs[1], "0");

    const float* b1e = b1 + (size_t)e * FF_;
#pragma unroll
    for (int mt = 0; mt < 4; mt++)
#pragma unroll
        for (int nt = 0; nt < 4; nt++) {
            int gn = n0 + wn * 64 + nt * 16 + l15;
            float bias = b1e[gn];
#pragma unroll
            for (int r = 0; r < 4; r++) {
                int gm = m0 + wm * 64 + mt * 16 + qd * 4 + r;
                act[(size_t)gm * FF_ + gn] = (bf16)gelu_f(acc[mt][nt][r] + bias);
            }
        }
}

// GEMM2: K=4096 (128 tiles), 4 buffers depth-2 (best measured variant, R4).
__global__ __launch_bounds__(256) void moe_gemm2_k(const bf16* __restrict__ act,
                                                   const bf16* __restrict__ w2t,
                                                   const float* __restrict__ b2,
                                                   const int* __restrict__ eoffp,
                                                   float* __restrict__ y) {
    int m0 = blockIdx.x * 128, n0 = blockIdx.y * 128;
    if (m0 >= eoffp[NE]) return;
    int e = 0;
#pragma unroll
    for (int i = 1; i < NE; i++) if (m0 >= eoffp[i]) e = i;

    __shared__ __align__(16) bf16 As[4][4096];
    __shared__ __align__(16) bf16 Bs[4][4096];
    int t = threadIdx.x;
    int wv = t >> 6, ln = t & 63;
    int wm = wv >> 1, wn = wv & 1, l15 = ln & 15, qd = ln >> 4;

    int sr0 = t >> 2, sr1 = 64 + sr0, cl = t & 3;
    int cs0 = (cl ^ ((sr0 >> 1) & 3)) * 8;
    int cs1 = (cl ^ ((sr1 >> 1) & 3)) * 8;
    const bf16* ga0 = act + (size_t)(m0 + sr0) * FF_ + cs0;
    const bf16* ga1 = act + (size_t)(m0 + sr1) * FF_ + cs1;
    const bf16* Bb = w2t + ((size_t)e * D_ + n0) * FF_;
    const bf16* gb0 = Bb + (size_t)sr0 * FF_ + cs0;
    const bf16* gb1 = Bb + (size_t)sr1 * FF_ + cs1;

    int ra_off[4], rb_off[4];
#pragma unroll
    for (int i = 0; i < 4; i++) {
        int r1 = wm * 64 + i * 16 + l15;
        ra_off[i] = r1 * 32 + (qd ^ ((r1 >> 1) & 3)) * 8;
        int r2 = wn * 64 + i * 16 + l15;
        rb_off[i] = r2 * 32 + (qd ^ ((r2 >> 1) & 3)) * 8;
    }

    f32x4 acc[4][4];
#pragma unroll
    for (int mt = 0; mt < 4; mt++)
#pragma unroll
        for (int nt = 0; nt < 4; nt++) acc[mt][nt] = (f32x4){0.f, 0.f, 0.f, 0.f};

    MOE_STAGE(As[0], Bs[0], 0);                 // tile 0
    MOE_STAGE(As[1], Bs[1], 32);                // tile 1; outstanding 8
    for (int k0 = 0; k0 < 3968; k0 += 128) {
        MOE_STAGE(As[2], Bs[2], k0 + 64);  MOE_STEP(As[0], Bs[0], "8");
        MOE_STAGE(As[3], Bs[3], k0 + 96);  MOE_STEP(As[1], Bs[1], "8");
        MOE_STAGE(As[0], Bs[0], k0 + 128); MOE_STEP(As[2], Bs[2], "8");
        MOE_STAGE(As[1], Bs[1], k0 + 160); MOE_STEP(As[3], Bs[3], "8");
    }
    MOE_STAGE(As[2], Bs[2], 4032); MOE_STEP(As[0], Bs[0], "8");
    MOE_STAGE(As[3], Bs[3], 4064); MOE_STEP(As[1], Bs[1], "8");
    MOE_STEP(As[2], Bs[2], "4");
    MOE_STEP(As[3], Bs[3], "0");

    const float* b2e = b2 + (size_t)e * D_;
#pragma unroll
    for (int mt = 0; mt < 4; mt++)
#pragma unroll
        for (int nt = 0; nt < 4; nt++) {
            int gn = n0 + wn * 64 + nt * 16 + l15;
            float bias = b2e[gn];
#pragma unroll
            for (int r = 0; r < 4; r++) {
                int gm = m0 + wm * 64 + mt * 16 + qd * 4 + r;
                y[(size_t)gm * D_ + gn] = acc[mt][nt][r] + bias;
            }
        }
}

// combine: out[tok] += g0*y[s0] + g1*y[s1]. One block per token.
__global__ __launch_bounds__(256) void combine_k(const float* __restrict__ y,
                                                 const int* __restrict__ sidx,
                                                 const float* __restrict__ tgate,
                                                 float* __restrict__ out) {
    int tok = blockIdx.x;
    int d = threadIdx.x * 4;
    int s0 = sidx[tok * 2], s1 = sidx[tok * 2 + 1];
    float g0 = tgate[tok * 2], g1 = tgate[tok * 2 + 1];
    float4 a = *(const float4*)(y + (size_t)s0 * D_ + d);
    float4 b = *(const float4*)(y + (size_t)s1 * D_ + d);
    float4 o = *(const float4*)(out + (size_t)tok * D_ + d);
    o.x += g0 * a.x + g1 * b.x;
    o.y += g0 * a.y + g1 * b.y;
    o.z += g0 * a.z + g1 * b.z;
    o.w += g0 * a.w + g1 * b.w;
    *(float4*)(out + (size_t)tok * D_ + d) = o;
}

// ---------------------------------------------------------------------------
extern "C" void kernel_launch(void* const* d_in, const int* in_sizes, int n_in,
                              void* d_out, int out_size, void* d_ws, size_t ws_size,
                              hipStream_t stream) {
    const float* x   = (const float*)d_in[0];
    const float* anw = (const float*)d_in[1];
    const float* wq  = (const float*)d_in[2];
    const float* wk  = (const float*)d_in[3];
    const float* wv  = (const float*)d_in[4];
    const float* wo  = (const float*)d_in[5];
    const float* mnw = (const float*)d_in[6];
    const float* rw  = (const float*)d_in[7];
    const float* w1  = (const float*)d_in[8];
    const float* b1  = (const float*)d_in[9];
    const float* w2  = (const float*)d_in[10];
    const float* b2  = (const float*)d_in[11];
    float* out = (float*)d_out;

    char* p = (char*)d_ws;
    auto take = [&](size_t n) { char* r = p; p += (n + 255) & ~(size_t)255; return r; };
    bf16* h1h = (bf16*)take((size_t)OUTN * 2);
    bf16* h1l = (bf16*)take((size_t)OUTN * 2);
    bf16* qh  = (bf16*)take((size_t)OUTN * 2);
    bf16* ql  = (bf16*)take((size_t)OUTN * 2);
    bf16* kh  = (bf16*)take((size_t)OUTN * 2);
    bf16* kl  = (bf16*)take((size_t)OUTN * 2);
    bf16* vh  = (bf16*)take((size_t)OUTN * 2);
    bf16* vl  = (bf16*)take((size_t)OUTN * 2);
    bf16* wqth = (bf16*)take((size_t)D_ * D_ * 2);
    bf16* wqtl = (bf16*)take((size_t)D_ * D_ * 2);
    bf16* wkth = (bf16*)take((size_t)D_ * D_ * 2);
    bf16* wktl = (bf16*)take((size_t)D_ * D_ * 2);
    bf16* wvth = (bf16*)take((size_t)D_ * D_ * 2);
    bf16* wvtl = (bf16*)take((size_t)D_ * D_ * 2);
    bf16* woth = (bf16*)take((size_t)D_ * D_ * 2);
    bf16* wotl = (bf16*)take((size_t)D_ * D_ * 2);
    bf16* w1t = (bf16*)take((size_t)NE * FF_ * D_ * 2);
    bf16* w2t = (bf16*)take((size_t)NE * FF_ * D_ * 2);
    bf16* act = (bf16*)take((size_t)CAP * FF_ * 2);
    int*   tidx  = (int*)take(NTOK * 2 * 4);
    float* tgate = (float*)take(NTOK * 2 * 4);
    int*   sidx  = (int*)take(NTOK * 2 * 4);
    int*   ecnt  = (int*)take(64);
    int*   ecnt2 = (int*)take(64);
    float* psum  = (float*)take(64);
    int*   eoffp = (int*)take(64);
    int*   stok  = (int*)take(CAP * 4);

    // aliases over dead buffers:
    bf16*  aoh = h1h;            // h1 dead after QKV gemm
    bf16*  aol = h1l;
    float* h_f = (float*)qh;     // q dead after attention (spans qh+ql, 8 MB)
    bf16*  h_b = kh;             // k dead after attention
    float* y   = (float*)vh;     // v + attn weight splits dead after WO: 8+16=24 MB >= CAP*D*4=21 MB

    hipMemsetAsync(ecnt, 0, NE * 4, stream);
    hipMemsetAsync(psum, 0, NE * 4, stream);
    hipMemsetAsync(stok, 0, CAP * 4, stream);
    // preload out with X (WO accumulates into it via atomics, split-K=4)
    hipMemcpyAsync(out, x, (size_t)OUTN * 4, hipMemcpyDeviceToDevice, stream);

    // weight transposes
    trans_split_k<<<dim3(32, 32, 4), 256, 0, stream>>>(wq, wk, wv, wo,
        wqth, wqtl, wkth, wktl, wvth, wvtl, woth, wotl);
    transpose_cast4_k<<<dim3(FF_ / 64, D_ / 64, NE), 256, 0, stream>>>(w1, w1t, D_, FF_);
    transpose_cast4_k<<<dim3(D_ / 64, FF_ / 64, NE), 256, 0, stream>>>(w2, w2t, FF_, D_);

    // attention path (split-bf16 MFMA, fp32 fidelity for router)
    rmsnorm_k<<<NTOK, 256, 0, stream>>>(x, anw, nullptr, h1h, h1l);
    gemm_qkv_k<<<dim3(16, 24), 256, 0, stream>>>(h1h, h1l,
        wqth, wqtl, wkth, wktl, wvth, wvtl, qh, ql, kh, kl, vh, vl);
    attn_mfma_k<<<dim3(16, 16, 2), 256, 0, stream>>>(qh, ql, kh, kl, vh, vl, aoh, aol);
    gemm_wo_k<<<dim3(16, 8, 4), 256, 0, stream>>>(aoh, aol, woth, wotl, out);

    // MoE
    rmsnorm_k<<<NTOK, 256, 0, stream>>>(out, mnw, h_f, h_b, nullptr);
    router_k<<<NTOK / 4, 256, 0, stream>>>(h_f, rw, tidx, tgate, ecnt, psum);
    passb_k<<<1, 64, 0, stream>>>(ecnt, psum, eoffp, ecnt2, out + OUTN);
    scatter_k<<<NTOK / 256, 256, 0, stream>>>(tidx, eoffp, ecnt2, stok, sidx);
    moe_gemm1_k<<<dim3(CAP / 128, FF_ / 128), 256, 0, stream>>>(h_b, w1t, b1, eoffp, stok, act);
    moe_gemm2_k<<<dim3(CAP / 128, D_ / 128), 256, 0, stream>>>(act, w2t, b2, eoffp, y);
    combine_k<<<NTOK, 256, 0, stream>>>(y, sidx, tgate, out);
}

// Round 7
// 742.272 us; speedup vs baseline: 1.0720x; 1.0456x over previous
//
#include <hip/hip_runtime.h>

typedef __bf16 bf16;
typedef __bf16 bf16x4 __attribute__((ext_vector_type(4)));
typedef __bf16 bf16x8 __attribute__((ext_vector_type(8)));
typedef float f32x4 __attribute__((ext_vector_type(4)));

#define D_   1024
#define S_   1024
#define B_   2
#define NTOK 2048
#define FF_  4096
#define NE   8
#define CAP  5120
#define OUTN 2097152

// fast tanh-form GELU: one v_exp_f32 instead of libm tanhf.
__device__ __forceinline__ float gelu_f(float x) {
    float u = 0.7978845608028654f * (x + 0.044715f * x * x * x);
    float a = fabsf(u);
    float e = __expf(-2.0f * a);
    float t = (1.0f - e) / (1.0f + e);
    t = copysignf(t, u);
    return 0.5f * x * (1.0f + t);
}

// async global->LDS, 16B per lane. LDS dest must be wave-uniform base; HW adds lane*16.
__device__ __forceinline__ void gload16(const void* g, void* l) {
    __builtin_amdgcn_global_load_lds((const __attribute__((address_space(1))) unsigned int*)g,
                                     (__attribute__((address_space(3))) unsigned int*)l,
                                     16, 0, 0);
}

// counted vmem wait (T4): keep N loads in flight across the barrier.
#define VMCNT(n) asm volatile("s_waitcnt vmcnt(" n ")" ::: "memory")
// raw barrier with compiler-level memory fences (no vmcnt(0) drain).
#define BARRIER() do { asm volatile("" ::: "memory"); \
                       __builtin_amdgcn_s_barrier();  \
                       asm volatile("" ::: "memory"); } while (0)

// ---------------------------------------------------------------------------
// RMSNorm: one block per row of 1024. Optional fp32 / bf16-hi / bf16-lo outs.
// ---------------------------------------------------------------------------
__global__ __launch_bounds__(256) void rmsnorm_k(const float* __restrict__ x,
                                                 const float* __restrict__ w,
                                                 float* __restrict__ yf,
                                                 bf16* __restrict__ yhi,
                                                 bf16* __restrict__ ylo) {
    int row = blockIdx.x;
    int t = threadIdx.x;
    const float* xr = x + (size_t)row * D_;
    float4 v = *(const float4*)(xr + t * 4);
    float ss = v.x * v.x + v.y * v.y + v.z * v.z + v.w * v.w;
    for (int off = 32; off; off >>= 1) ss += __shfl_down(ss, off);
    __shared__ float wsum[4];
    if ((t & 63) == 0) wsum[t >> 6] = ss;
    __syncthreads();
    float tot = wsum[0] + wsum[1] + wsum[2] + wsum[3];
    float rr = rsqrtf(tot * (1.0f / D_) + 1e-6f);
    float4 wv = *(const float4*)(w + t * 4);
    float y[4];
    y[0] = v.x * rr * wv.x; y[1] = v.y * rr * wv.y;
    y[2] = v.z * rr * wv.z; y[3] = v.w * rr * wv.w;
    if (yf) *(float4*)(yf + (size_t)row * D_ + t * 4) = *(float4*)y;
    if (yhi) {
#pragma unroll
        for (int i = 0; i < 4; i++) {
            bf16 hi = (bf16)y[i];
            yhi[(size_t)row * D_ + t * 4 + i] = hi;
            if (ylo) ylo[(size_t)row * D_ + t * 4 + i] = (bf16)(y[i] - (float)hi);
        }
    }
}

// ---------------------------------------------------------------------------
// Transpose + split-cast fp32 [1024][1024] -> bf16 hi/lo [N][K]. (attn weights)
// ---------------------------------------------------------------------------
__global__ __launch_bounds__(256) void trans_split_k(
    const float* __restrict__ w0, const float* __restrict__ w1p,
    const float* __restrict__ w2p, const float* __restrict__ w3,
    bf16* o0h, bf16* o0l, bf16* o1h, bf16* o1l,
    bf16* o2h, bf16* o2l, bf16* o3h, bf16* o3l) {
    int z = blockIdx.z;
    const float* src = (z == 0) ? w0 : (z == 1) ? w1p : (z == 2) ? w2p : w3;
    bf16* dh = (z == 0) ? o0h : (z == 1) ? o1h : (z == 2) ? o2h : o3h;
    bf16* dl = (z == 0) ? o0l : (z == 1) ? o1l : (z == 2) ? o2l : o3l;
    __shared__ float tl[32][33];
    int c0 = blockIdx.x * 32, r0 = blockIdx.y * 32;
    int tx = threadIdx.x & 31, ty = threadIdx.x >> 5;
#pragma unroll
    for (int i = 0; i < 4; i++) {
        int r = ty + i * 8;
        tl[r][tx] = src[(size_t)(r0 + r) * 1024 + c0 + tx];
    }
    __syncthreads();
#pragma unroll
    for (int i = 0; i < 4; i++) {
        int c = ty + i * 8;
        float v = tl[tx][c];
        bf16 hi = (bf16)v;
        dh[(size_t)(c0 + c) * 1024 + r0 + tx] = hi;
        dl[(size_t)(c0 + c) * 1024 + r0 + tx] = (bf16)(v - (float)hi);
    }
}

// ---------------------------------------------------------------------------
// Vectorized transpose + cast fp32 -> bf16: in [z][R][C] -> out [z][C][R].
// 64x64 tile, float4 loads (16B/lane), bf16x4 stores (8B/lane).  (MoE weights)
// ---------------------------------------------------------------------------
__global__ __launch_bounds__(256) void transpose_cast4_k(const float* __restrict__ in,
                                                         bf16* __restrict__ out,
                                                         int R, int C) {
    __shared__ float tl[64][65];
    size_t base = (size_t)blockIdx.z * R * C;
    const float* src = in + base;
    bf16* dst = out + base;
    int c0 = blockIdx.x * 64, r0 = blockIdx.y * 64;
    int t = threadIdx.x;
    int lr = t >> 4;            // 0..15
    int lc = (t & 15) * 4;      // 0,4,..,60
#pragma unroll
    for (int i = 0; i < 4; i++) {
        int r = lr + i * 16;
        float4 v = *(const float4*)(src + (size_t)(r0 + r) * C + c0 + lc);
        tl[r][lc] = v.x; tl[r][lc + 1] = v.y; tl[r][lc + 2] = v.z; tl[r][lc + 3] = v.w;
    }
    __syncthreads();
    int wc = t >> 4;            // col 0..15 (+16*i)
    int wr = (t & 15) * 4;      // row chunk 0,4,..,60
#pragma unroll
    for (int i = 0; i < 4; i++) {
        int c = wc + i * 16;
        bf16x4 o;
        o[0] = (bf16)tl[wr][c];     o[1] = (bf16)tl[wr + 1][c];
        o[2] = (bf16)tl[wr + 2][c]; o[3] = (bf16)tl[wr + 3][c];
        *(bf16x4*)(dst + (size_t)(c0 + c) * R + r0 + wr) = o;
    }
}

// ---------------------------------------------------------------------------
// V transpose: vh/vl [B*S][D] -> vth/vtl [(b*16+h)*64+dh][S]. 64x64 LDS tile.
// Lets attention stage V^T via global_load_lds (kills the 16-way-conflicted
// scalar LDS transpose-writes that dominated attn staging).
// ---------------------------------------------------------------------------
__global__ __launch_bounds__(256) void vtrans_k(const bf16* __restrict__ vh,
                                                const bf16* __restrict__ vl,
                                                bf16* __restrict__ vth,
                                                bf16* __restrict__ vtl) {
    int s0 = blockIdx.x * 64;          // seq tile base
    int bh = blockIdx.y;               // b*16+h
    int b = bh >> 4, h = bh & 15;
    const bf16* src = blockIdx.z ? vl : vh;
    bf16* dst = blockIdx.z ? vtl : vth;
    __shared__ bf16 tl[64][65];
    int t = threadIdx.x;
    int lr = t >> 4, lc = (t & 15) * 4;
#pragma unroll
    for (int i = 0; i < 4; i++) {
        int r = lr + i * 16;
        bf16x4 v = *(const bf16x4*)(src + (size_t)(b * S_ + s0 + r) * D_ + h * 64 + lc);
        tl[r][lc] = v[0]; tl[r][lc + 1] = v[1]; tl[r][lc + 2] = v[2]; tl[r][lc + 3] = v[3];
    }
    __syncthreads();
    int wc = t >> 4, wr = (t & 15) * 4;
#pragma unroll
    for (int i = 0; i < 4; i++) {
        int c = wc + i * 16;           // dh
        bf16x4 o;
        o[0] = tl[wr][c];     o[1] = tl[wr + 1][c];
        o[2] = tl[wr + 2][c]; o[3] = tl[wr + 3][c];
        *(bf16x4*)(dst + (size_t)(bh * 64 + c) * S_ + s0 + wr) = o;
    }
}

// ---------------------------------------------------------------------------
// Split-bf16 dense GEMM, 128x128 tile, BK=32, 4 waves 2x2.
// A hi/lo [M][K=1024], B hi/lo [N][K=1024]. global_load_lds + XOR swizzle +
// T4 counted-vmcnt pipeline. 3-product Markidis MFMA. (unchanged from R6)
// ---------------------------------------------------------------------------
#define SPLIT_STAGE(bi, k0)                             \
    gload16(gah0 + (k0), Lah[bi] + wv * 512);           \
    gload16(gah1 + (k0), Lah[bi] + 2048 + wv * 512);    \
    gload16(gal0 + (k0), Lal[bi] + wv * 512);           \
    gload16(gal1 + (k0), Lal[bi] + 2048 + wv * 512);    \
    gload16(gbh0 + (k0), Lbh[bi] + wv * 512);           \
    gload16(gbh1 + (k0), Lbh[bi] + 2048 + wv * 512);    \
    gload16(gbl0 + (k0), Lbl[bi] + wv * 512);           \
    gload16(gbl1 + (k0), Lbl[bi] + 2048 + wv * 512);

#define SPLIT_COMPUTE(bi) {                                                            \
    bf16x8 fah[4], fal[4], fbh[4], fbl[4];                                             \
    _Pragma("unroll") for (int i = 0; i < 4; i++) {                                    \
        fah[i] = *(const bf16x8*)(Lah[bi] + ra_off[i]);                                \
        fal[i] = *(const bf16x8*)(Lal[bi] + ra_off[i]);                                \
        fbh[i] = *(const bf16x8*)(Lbh[bi] + rb_off[i]);                                \
        fbl[i] = *(const bf16x8*)(Lbl[bi] + rb_off[i]);                                \
    }                                                                                  \
    _Pragma("unroll") for (int mt = 0; mt < 4; mt++)                                   \
    _Pragma("unroll") for (int nt = 0; nt < 4; nt++) {                                 \
        acc[mt][nt] = __builtin_amdgcn_mfma_f32_16x16x32_bf16(fah[mt], fbh[nt], acc[mt][nt], 0, 0, 0); \
        acc[mt][nt] = __builtin_amdgcn_mfma_f32_16x16x32_bf16(fah[mt], fbl[nt], acc[mt][nt], 0, 0, 0); \
        acc[mt][nt] = __builtin_amdgcn_mfma_f32_16x16x32_bf16(fal[mt], fbh[nt], acc[mt][nt], 0, 0, 0); \
    } }

#define SPLIT_STEP(bi, VM)          \
    VMCNT(VM);                      \
    BARRIER();                      \
    SPLIT_COMPUTE(bi);              \
    BARRIER();

#define SPLIT_DECLS(KOFF)                                                              \
    __shared__ __align__(16) bf16 Lah[2][4096];                                        \
    __shared__ __align__(16) bf16 Lal[2][4096];                                        \
    __shared__ __align__(16) bf16 Lbh[2][4096];                                        \
    __shared__ __align__(16) bf16 Lbl[2][4096];                                        \
    int t = threadIdx.x;                                                               \
    int wv = t >> 6, ln = t & 63;                                                      \
    int wm = wv >> 1, wn = wv & 1, l15 = ln & 15, qd = ln >> 4;                        \
    int sr0 = t >> 2, sr1 = 64 + sr0, cl = t & 3;                                      \
    int cs0 = (cl ^ ((sr0 >> 1) & 3)) * 8;                                             \
    int cs1 = (cl ^ ((sr1 >> 1) & 3)) * 8;                                             \
    const bf16* gah0 = Ah + (size_t)(m0 + sr0) * 1024 + (KOFF) + cs0;                  \
    const bf16* gah1 = Ah + (size_t)(m0 + sr1) * 1024 + (KOFF) + cs1;                  \
    const bf16* gal0 = Al + (size_t)(m0 + sr0) * 1024 + (KOFF) + cs0;                  \
    const bf16* gal1 = Al + (size_t)(m0 + sr1) * 1024 + (KOFF) + cs1;                  \
    const bf16* gbh0 = Bh + (size_t)(n0 + sr0) * 1024 + (KOFF) + cs0;                  \
    const bf16* gbh1 = Bh + (size_t)(n0 + sr1) * 1024 + (KOFF) + cs1;                  \
    const bf16* gbl0 = Bl + (size_t)(n0 + sr0) * 1024 + (KOFF) + cs0;                  \
    const bf16* gbl1 = Bl + (size_t)(n0 + sr1) * 1024 + (KOFF) + cs1;                  \
    int ra_off[4], rb_off[4];                                                          \
    _Pragma("unroll") for (int i = 0; i < 4; i++) {                                    \
        int r1 = wm * 64 + i * 16 + l15;                                               \
        ra_off[i] = r1 * 32 + (qd ^ ((r1 >> 1) & 3)) * 8;                              \
        int r2 = wn * 64 + i * 16 + l15;                                               \
        rb_off[i] = r2 * 32 + (qd ^ ((r2 >> 1) & 3)) * 8;                              \
    }                                                                                  \
    f32x4 acc[4][4];                                                                   \
    _Pragma("unroll") for (int mt = 0; mt < 4; mt++)                                   \
    _Pragma("unroll") for (int nt = 0; nt < 4; nt++) acc[mt][nt] = (f32x4){0.f,0.f,0.f,0.f};

// QKV: grid (16, 24): y = weight*8 + n-tile. K=1024 (32 tiles). Outputs hi/lo.
__global__ __launch_bounds__(256) void gemm_qkv_k(
    const bf16* __restrict__ Ah, const bf16* __restrict__ Al,
    const bf16* __restrict__ Bqh, const bf16* __restrict__ Bql,
    const bf16* __restrict__ Bkh, const bf16* __restrict__ Bkl,
    const bf16* __restrict__ Bvh, const bf16* __restrict__ Bvl,
    bf16* Cqh, bf16* Cql, bf16* Ckh, bf16* Ckl, bf16* Cvh, bf16* Cvl) {
    int gy = blockIdx.y, zw = gy >> 3;
    const bf16* Bh = (zw == 0) ? Bqh : (zw == 1) ? Bkh : Bvh;
    const bf16* Bl = (zw == 0) ? Bql : (zw == 1) ? Bkl : Bvl;
    bf16* Ch = (zw == 0) ? Cqh : (zw == 1) ? Ckh : Cvh;
    bf16* Cl = (zw == 0) ? Cql : (zw == 1) ? Ckl : Cvl;
    int m0 = blockIdx.x * 128, n0 = (gy & 7) * 128;
    SPLIT_DECLS(0)
    SPLIT_STAGE(0, 0);
    for (int k0 = 0; k0 < 960; k0 += 64) {
        SPLIT_STAGE(1, k0 + 32);
        SPLIT_STEP(0, "8");
        SPLIT_STAGE(0, k0 + 64);
        SPLIT_STEP(1, "8");
    }
    SPLIT_STAGE(1, 992);
    SPLIT_STEP(0, "8");
    SPLIT_STEP(1, "0");
#pragma unroll
    for (int mt = 0; mt < 4; mt++)
#pragma unroll
        for (int nt = 0; nt < 4; nt++)
#pragma unroll
            for (int r = 0; r < 4; r++) {
                int gm = m0 + wm * 64 + mt * 16 + qd * 4 + r;
                int gn = n0 + wn * 64 + nt * 16 + l15;
                float vv = acc[mt][nt][r];
                bf16 hi = (bf16)vv;
                Ch[(size_t)gm * D_ + gn] = hi;
                Cl[(size_t)gm * D_ + gn] = (bf16)(vv - (float)hi);
            }
}

// WO: grid (16, 8, 4) SPLIT-K=4. C pre-filled with X; fp32 atomicAdd partials.
__global__ __launch_bounds__(256) void gemm_wo_k(
    const bf16* __restrict__ Ah, const bf16* __restrict__ Al,
    const bf16* __restrict__ Bh, const bf16* __restrict__ Bl,
    float* __restrict__ C) {
    int m0 = blockIdx.x * 128, n0 = blockIdx.y * 128;
    int kb = blockIdx.z * 256;
    SPLIT_DECLS(kb)
    SPLIT_STAGE(0, 0);
    for (int k0 = 0; k0 < 192; k0 += 64) {
        SPLIT_STAGE(1, k0 + 32);
        SPLIT_STEP(0, "8");
        SPLIT_STAGE(0, k0 + 64);
        SPLIT_STEP(1, "8");
    }
    SPLIT_STAGE(1, 224);
    SPLIT_STEP(0, "8");
    SPLIT_STEP(1, "0");
#pragma unroll
    for (int mt = 0; mt < 4; mt++)
#pragma unroll
        for (int nt = 0; nt < 4; nt++)
#pragma unroll
            for (int r = 0; r < 4; r++) {
                int gm = m0 + wm * 64 + mt * 16 + qd * 4 + r;
                int gn = n0 + wn * 64 + nt * 16 + l15;
                atomicAdd(&C[(size_t)gm * D_ + gn], acc[mt][nt][r]);
            }
}

// ---------------------------------------------------------------------------
// Split-bf16 MFMA flash attention. Block = (qt desc, h, b): 64 q-rows, 4 waves.
// K and V^T tiles staged via global_load_lds into linear [64][64] LDS with
// both-sides XOR chunk swizzle (chunk ^= row&7) -> zero LDS-write instructions,
// conflict-free ds_read_b128. V^T comes pre-transposed from vtrans_k.
// ---------------------------------------------------------------------------
#define AP 72

__global__ __launch_bounds__(256) void attn_mfma_k(
    const bf16* __restrict__ qhp, const bf16* __restrict__ qlp,
    const bf16* __restrict__ khp, const bf16* __restrict__ klp,
    const bf16* __restrict__ vth, const bf16* __restrict__ vtl,
    bf16* __restrict__ aoh, bf16* __restrict__ aol) {
    int qt = (int)gridDim.x - 1 - (int)blockIdx.x;  // deep tiles first
    int h = blockIdx.y, b = blockIdx.z;
    __shared__ __align__(16) bf16 Ksh[4096], Ksl[4096], VTh[4096], VTl[4096];
    __shared__ bf16 Ph[4][16 * AP], Pl[4][16 * AP];
    int t = threadIdx.x, wv = t >> 6, ln = t & 63, l15 = ln & 15, qd = ln >> 4;

    bf16x8 aqh[2], aql[2];
    {
        size_t qb = ((size_t)(b * S_ + qt * 64 + wv * 16 + l15)) * D_ + h * 64 + qd * 8;
        aqh[0] = *(const bf16x8*)(qhp + qb);
        aqh[1] = *(const bf16x8*)(qhp + qb + 32);
        aql[0] = *(const bf16x8*)(qlp + qb);
        aql[1] = *(const bf16x8*)(qlp + qb + 32);
    }

    // staging: thread t owns slots t and t+256; slot s -> row=s>>3, chunk=s&7.
    // global chunk = chunk ^ (row&7)  (swizzle inverse; rows+32 share row&7).
    int srow = t >> 3, scl = t & 7;
    int gsc = (scl ^ (srow & 7)) * 8;
    const bf16* kh0 = khp + (size_t)(b * S_ + srow) * D_ + h * 64 + gsc;
    const bf16* kh1 = khp + (size_t)(b * S_ + srow + 32) * D_ + h * 64 + gsc;
    const bf16* kl0 = klp + (size_t)(b * S_ + srow) * D_ + h * 64 + gsc;
    const bf16* kl1 = klp + (size_t)(b * S_ + srow + 32) * D_ + h * 64 + gsc;
    const bf16* vt0 = vth + (size_t)((b * 16 + h) * 64 + srow) * S_ + gsc;
    const bf16* vt1 = vth + (size_t)((b * 16 + h) * 64 + srow + 32) * S_ + gsc;
    const bf16* wl0 = vtl + (size_t)((b * 16 + h) * 64 + srow) * S_ + gsc;
    const bf16* wl1 = vtl + (size_t)((b * 16 + h) * 64 + srow + 32) * S_ + gsc;

    // loop-invariant swizzled read offsets (identical formula for K and VT)
    int soff[4][2];
#pragma unroll
    for (int nt = 0; nt < 4; nt++)
#pragma unroll
        for (int ks = 0; ks < 2; ks++) {
            int r = nt * 16 + l15;
            soff[nt][ks] = r * 64 + ((ks * 4 + qd) ^ (r & 7)) * 8;
        }

    f32x4 oacc[4];
    float mrow[4], lrow[4];
#pragma unroll
    for (int i = 0; i < 4; i++) {
        oacc[i] = (f32x4){0.f, 0.f, 0.f, 0.f};
        mrow[i] = -1e30f; lrow[i] = 0.0f;
    }

    for (int kt = 0; kt <= qt; kt++) {
        BARRIER();                       // all waves done reading previous tile
        size_t ko = (size_t)kt * 64 * D_;
        int vo = kt * 64;
        gload16(kh0 + ko, Ksh + wv * 512); gload16(kh1 + ko, Ksh + 2048 + wv * 512);
        gload16(kl0 + ko, Ksl + wv * 512); gload16(kl1 + ko, Ksl + 2048 + wv * 512);
        gload16(vt0 + vo, VTh + wv * 512); gload16(vt1 + vo, VTh + 2048 + wv * 512);
        gload16(wl0 + vo, VTl + wv * 512); gload16(wl1 + vo, VTl + 2048 + wv * 512);
        VMCNT("0");
        BARRIER();

        f32x4 sacc[4];
#pragma unroll
        for (int nt = 0; nt < 4; nt++) sacc[nt] = (f32x4){0.f, 0.f, 0.f, 0.f};
#pragma unroll
        for (int ks = 0; ks < 2; ks++) {
#pragma unroll
            for (int nt = 0; nt < 4; nt++) {
                bf16x8 bh = *(const bf16x8*)&Ksh[soff[nt][ks]];
                bf16x8 bl = *(const bf16x8*)&Ksl[soff[nt][ks]];
                sacc[nt] = __builtin_amdgcn_mfma_f32_16x16x32_bf16(aqh[ks], bh, sacc[nt], 0, 0, 0);
                sacc[nt] = __builtin_amdgcn_mfma_f32_16x16x32_bf16(aqh[ks], bl, sacc[nt], 0, 0, 0);
                sacc[nt] = __builtin_amdgcn_mfma_f32_16x16x32_bf16(aql[ks], bh, sacc[nt], 0, 0, 0);
            }
        }
        bool diag = (kt == qt);
#pragma unroll
        for (int r = 0; r < 4; r++) {
            float s0[4];
#pragma unroll
            for (int nt = 0; nt < 4; nt++) {
                s0[nt] = sacc[nt][r] * 0.125f;
                if (diag && (nt * 16 + l15) > (wv * 16 + qd * 4 + r)) s0[nt] = -1e30f;
            }
            float vmax = fmaxf(fmaxf(s0[0], s0[1]), fmaxf(s0[2], s0[3]));
            for (int off = 1; off < 16; off <<= 1) vmax = fmaxf(vmax, __shfl_xor(vmax, off));
            float mnew = fmaxf(mrow[r], vmax);
            float alpha = __expf(mrow[r] - mnew);
            float p[4], rs = 0.0f;
#pragma unroll
            for (int nt = 0; nt < 4; nt++) { p[nt] = __expf(s0[nt] - mnew); rs += p[nt]; }
            for (int off = 1; off < 16; off <<= 1) rs += __shfl_xor(rs, off);
            lrow[r] = lrow[r] * alpha + rs;
            mrow[r] = mnew;
#pragma unroll
            for (int nt = 0; nt < 4; nt++) oacc[nt][r] *= alpha;
            int prow = qd * 4 + r;
#pragma unroll
            for (int nt = 0; nt < 4; nt++) {
                bf16 hi = (bf16)p[nt];
                Ph[wv][prow * AP + nt * 16 + l15] = hi;
                Pl[wv][prow * AP + nt * 16 + l15] = (bf16)(p[nt] - (float)hi);
            }
        }
        // PV: same-wave LDS RAW (in-order DS pipe), no barrier needed.
#pragma unroll
        for (int ks2 = 0; ks2 < 2; ks2++) {
            bf16x8 aph = *(const bf16x8*)&Ph[wv][l15 * AP + ks2 * 32 + qd * 8];
            bf16x8 apl = *(const bf16x8*)&Pl[wv][l15 * AP + ks2 * 32 + qd * 8];
#pragma unroll
            for (int nt = 0; nt < 4; nt++) {
                bf16x8 bvh = *(const bf16x8*)&VTh[soff[nt][ks2]];
                bf16x8 bvl = *(const bf16x8*)&VTl[soff[nt][ks2]];
                oacc[nt] = __builtin_amdgcn_mfma_f32_16x16x32_bf16(aph, bvh, oacc[nt], 0, 0, 0);
                oacc[nt] = __builtin_amdgcn_mfma_f32_16x16x32_bf16(aph, bvl, oacc[nt], 0, 0, 0);
                oacc[nt] = __builtin_amdgcn_mfma_f32_16x16x32_bf16(apl, bvh, oacc[nt], 0, 0, 0);
            }
        }
    }

#pragma unroll
    for (int r = 0; r < 4; r++) {
        float inv = 1.0f / lrow[r];
        size_t rowa = ((size_t)(b * S_ + qt * 64 + wv * 16 + qd * 4 + r)) * D_ + h * 64;
#pragma unroll
        for (int nt = 0; nt < 4; nt++) {
            float o = oacc[nt][r] * inv;
            bf16 hi = (bf16)o;
            aoh[rowa + nt * 16 + l15] = hi;
            aol[rowa + nt * 16 + l15] = (bf16)(o - (float)hi);
        }
    }
}

// ---------------------------------------------------------------------------
// Router: 4 tokens/block (wave each). fp32 logits -> softmax -> top2.
// ---------------------------------------------------------------------------
__global__ __launch_bounds__(256) void router_k(const float* __restrict__ h,
                                                const float* __restrict__ rw,
                                                int* __restrict__ tidx,
                                                float* __restrict__ tgate,
                                                int* __restrict__ ecnt,
                                                float* __restrict__ psum) {
    int wv = threadIdx.x >> 6, ln = threadIdx.x & 63;
    int tok = blockIdx.x * 4 + wv;
    const float* hr = h + (size_t)tok * D_;
    float acc[NE];
#pragma unroll
    for (int e = 0; e < NE; e++) acc[e] = 0.0f;
    int base = ln * 16;
#pragma unroll
    for (int c = 0; c < 4; c++) {
        float4 hv = *(const float4*)(hr + base + c * 4);
        const float* rp = rw + (size_t)(base + c * 4) * NE;
        float hx[4] = {hv.x, hv.y, hv.z, hv.w};
#pragma unroll
        for (int jj = 0; jj < 4; jj++)
#pragma unroll
            for (int e = 0; e < NE; e++)
                acc[e] = fmaf(hx[jj], rp[jj * NE + e], acc[e]);
    }
#pragma unroll
    for (int e = 0; e < NE; e++)
        for (int off = 32; off; off >>= 1) acc[e] += __shfl_down(acc[e], off);

    __shared__ float pb[4][NE];
    if (ln == 0) {
        float mx = acc[0];
#pragma unroll
        for (int e = 1; e < NE; e++) mx = fmaxf(mx, acc[e]);
        float p[NE], ssum = 0.0f;
#pragma unroll
        for (int e = 0; e < NE; e++) { p[e] = expf(acc[e] - mx); ssum += p[e]; }
        float inv = 1.0f / ssum;
#pragma unroll
        for (int e = 0; e < NE; e++) p[e] *= inv;
        int i0 = 0; float b0 = p[0];
#pragma unroll
        for (int e = 1; e < NE; e++) if (p[e] > b0) { b0 = p[e]; i0 = e; }
        int i1 = -1; float b1v = -1.0f;
#pragma unroll
        for (int e = 0; e < NE; e++) if (e != i0 && p[e] > b1v) { b1v = p[e]; i1 = e; }
        tidx[tok * 2] = i0; tidx[tok * 2 + 1] = i1;
        tgate[tok * 2] = b0; tgate[tok * 2 + 1] = b1v;
        atomicAdd(&ecnt[i0], 1);
        atomicAdd(&ecnt[i1], 1);
#pragma unroll
        for (int e = 0; e < NE; e++) pb[wv][e] = p[e];
    }
    __syncthreads();
    if (threadIdx.x < NE) {
        float s2 = pb[0][threadIdx.x] + pb[1][threadIdx.x] + pb[2][threadIdx.x] + pb[3][threadIdx.x];
        atomicAdd(&psum[threadIdx.x], s2);
    }
}

__global__ void passb_k(const int* __restrict__ ecnt, const float* __restrict__ psum,
                        int* __restrict__ eoffp, int* __restrict__ ecnt2,
                        float* __restrict__ out_tail) {
    if (threadIdx.x == 0) {
        int off = 0; float loss = 0.0f;
        for (int e = 0; e < NE; e++) {
            eoffp[e] = off;
            int c = ecnt[e];
            off += (c + 127) & ~127;
            loss += (c * (1.0f / 4096.0f)) * (psum[e] * (1.0f / 2048.0f));
            out_tail[1 + e] = (float)c;
            ecnt2[e] = 0;
        }
        eoffp[NE] = off;
        out_tail[0] = 8.0f * loss;
    }
}

// scatter: slot list per expert + inverse map (slot of each (tok,k)).
__global__ __launch_bounds__(256) void scatter_k(const int* __restrict__ tidx,
                                                 const int* __restrict__ eoffp,
                                                 int* __restrict__ ecnt2,
                                                 int* __restrict__ stok,
                                                 int* __restrict__ sidx) {
    int tok = blockIdx.x * 256 + threadIdx.x;
    for (int k = 0; k < 2; k++) {
        int e = tidx[tok * 2 + k];
        int pos = eoffp[e] + atomicAdd(&ecnt2[e], 1);
        stok[pos] = tok;
        sidx[tok * 2 + k] = pos;
    }
}

// ---------------------------------------------------------------------------
// MoE GEMMs with T4 counted-vmcnt pipelining. Both-sides XOR swizzle; linear LDS.
// ---------------------------------------------------------------------------
#define MOE_STAGE(bufA, bufB, k0)                       \
    gload16(ga0 + (k0), (bufA) + wv * 512);             \
    gload16(ga1 + (k0), (bufA) + 2048 + wv * 512);      \
    gload16(gb0 + (k0), (bufB) + wv * 512);             \
    gload16(gb1 + (k0), (bufB) + 2048 + wv * 512);

#define MOE_TILE(bufA, bufB) {                                                         \
    bf16x8 af[4], bfr[4];                                                              \
    _Pragma("unroll") for (int i = 0; i < 4; i++) {                                    \
        af[i]  = *(const bf16x8*)((bufA) + ra_off[i]);                                 \
        bfr[i] = *(const bf16x8*)((bufB) + rb_off[i]);                                 \
    }                                                                                  \
    _Pragma("unroll") for (int mt = 0; mt < 4; mt++)                                   \
    _Pragma("unroll") for (int nt = 0; nt < 4; nt++)                                   \
        acc[mt][nt] = __builtin_amdgcn_mfma_f32_16x16x32_bf16(af[mt], bfr[nt], acc[mt][nt], 0, 0, 0); }

#define MOE_STEP(rdA, rdB, VM)      \
    VMCNT(VM);                      \
    BARRIER();                      \
    MOE_TILE(rdA, rdB);             \
    BARRIER();

// GEMM1: K=1024 (32 tiles), 2 buffers depth-1. Grid (40,32)=1280 blocks (5/CU).
__global__ __launch_bounds__(256) void moe_gemm1_k(const bf16* __restrict__ hB,
                                                   const bf16* __restrict__ w1t,
                                                   const float* __restrict__ b1,
                                                   const int* __restrict__ eoffp,
                                                   const int* __restrict__ stok,
                                                   bf16* __restrict__ act) {
    int m0 = blockIdx.x * 128, n0 = blockIdx.y * 128;
    if (m0 >= eoffp[NE]) return;
    int e = 0;
#pragma unroll
    for (int i = 1; i < NE; i++) if (m0 >= eoffp[i]) e = i;

    __shared__ __align__(16) bf16 As[2][4096];
    __shared__ __align__(16) bf16 Bs[2][4096];
    int t = threadIdx.x;
    int wv = t >> 6, ln = t & 63;
    int wm = wv >> 1, wn = wv & 1, l15 = ln & 15, qd = ln >> 4;

    int sr0 = t >> 2, sr1 = 64 + sr0, cl = t & 3;
    int cs0 = (cl ^ ((sr0 >> 1) & 3)) * 8;
    int cs1 = (cl ^ ((sr1 >> 1) & 3)) * 8;
    const bf16* ga0 = hB + (size_t)stok[m0 + sr0] * D_ + cs0;
    const bf16* ga1 = hB + (size_t)stok[m0 + sr1] * D_ + cs1;
    const bf16* Bb = w1t + ((size_t)e * FF_ + n0) * D_;
    const bf16* gb0 = Bb + (size_t)sr0 * D_ + cs0;
    const bf16* gb1 = Bb + (size_t)sr1 * D_ + cs1;

    int ra_off[4], rb_off[4];
#pragma unroll
    for (int i = 0; i < 4; i++) {
        int r1 = wm * 64 + i * 16 + l15;
        ra_off[i] = r1 * 32 + (qd ^ ((r1 >> 1) & 3)) * 8;
        int r2 = wn * 64 + i * 16 + l15;
        rb_off[i] = r2 * 32 + (qd ^ ((r2 >> 1) & 3)) * 8;
    }

    f32x4 acc[4][4];
#pragma unroll
    for (int mt = 0; mt < 4; mt++)
#pragma unroll
        for (int nt = 0; nt < 4; nt++) acc[mt][nt] = (f32x4){0.f, 0.f, 0.f, 0.f};

    MOE_STAGE(As[0], Bs[0], 0);
    for (int k0 = 0; k0 < 960; k0 += 64) {
        MOE_STAGE(As[1], Bs[1], k0 + 32);
        MOE_STEP(As[0], Bs[0], "4");
        MOE_STAGE(As[0], Bs[0], k0 + 64);
        MOE_STEP(As[1], Bs[1], "4");
    }
    MOE_STAGE(As[1], Bs[1], 992);
    MOE_STEP(As[0], Bs[0], "4");
    MOE_STEP(As[1], Bs[1], "0");

    const float* b1e = b1 + (size_t)e * FF_;
#pragma unroll
    for (int mt = 0; mt < 4; mt++)
#pragma unroll
        for (int nt = 0; nt < 4; nt++) {
            int gn = n0 + wn * 64 + nt * 16 + l15;
            float bias = b1e[gn];
#pragma unroll
            for (int r = 0; r < 4; r++) {
                int gm = m0 + wm * 64 + mt * 16 + qd * 4 + r;
                act[(size_t)gm * FF_ + gn] = (bf16)gelu_f(acc[mt][nt][r] + bias);
            }
        }
}

// GEMM2: K=4096 (128 tiles), 4 buffers depth-2 (best measured variant, R4).
__global__ __launch_bounds__(256) void moe_gemm2_k(const bf16* __restrict__ act,
                                                   const bf16* __restrict__ w2t,
                                                   const float* __restrict__ b2,
                                                   const int* __restrict__ eoffp,
                                                   float* __restrict__ y) {
    int m0 = blockIdx.x * 128, n0 = blockIdx.y * 128;
    if (m0 >= eoffp[NE]) return;
    int e = 0;
#pragma unroll
    for (int i = 1; i < NE; i++) if (m0 >= eoffp[i]) e = i;

    __shared__ __align__(16) bf16 As[4][4096];
    __shared__ __align__(16) bf16 Bs[4][4096];
    int t = threadIdx.x;
    int wv = t >> 6, ln = t & 63;
    int wm = wv >> 1, wn = wv & 1, l15 = ln & 15, qd = ln >> 4;

    int sr0 = t >> 2, sr1 = 64 + sr0, cl = t & 3;
    int cs0 = (cl ^ ((sr0 >> 1) & 3)) * 8;
    int cs1 = (cl ^ ((sr1 >> 1) & 3)) * 8;
    const bf16* ga0 = act + (size_t)(m0 + sr0) * FF_ + cs0;
    const bf16* ga1 = act + (size_t)(m0 + sr1) * FF_ + cs1;
    const bf16* Bb = w2t + ((size_t)e * D_ + n0) * FF_;
    const bf16* gb0 = Bb + (size_t)sr0 * FF_ + cs0;
    const bf16* gb1 = Bb + (size_t)sr1 * FF_ + cs1;

    int ra_off[4], rb_off[4];
#pragma unroll
    for (int i = 0; i < 4; i++) {
        int r1 = wm * 64 + i * 16 + l15;
        ra_off[i] = r1 * 32 + (qd ^ ((r1 >> 1) & 3)) * 8;
        int r2 = wn * 64 + i * 16 + l15;
        rb_off[i] = r2 * 32 + (qd ^ ((r2 >> 1) & 3)) * 8;
    }

    f32x4 acc[4][4];
#pragma unroll
    for (int mt = 0; mt < 4; mt++)
#pragma unroll
        for (int nt = 0; nt < 4; nt++) acc[mt][nt] = (f32x4){0.f, 0.f, 0.f, 0.f};

    MOE_STAGE(As[0], Bs[0], 0);                 // tile 0
    MOE_STAGE(As[1], Bs[1], 32);                // tile 1; outstanding 8
    for (int k0 = 0; k0 < 3968; k0 += 128) {
        MOE_STAGE(As[2], Bs[2], k0 + 64);  MOE_STEP(As[0], Bs[0], "8");
        MOE_STAGE(As[3], Bs[3], k0 + 96);  MOE_STEP(As[1], Bs[1], "8");
        MOE_STAGE(As[0], Bs[0], k0 + 128); MOE_STEP(As[2], Bs[2], "8");
        MOE_STAGE(As[1], Bs[1], k0 + 160); MOE_STEP(As[3], Bs[3], "8");
    }
    MOE_STAGE(As[2], Bs[2], 4032); MOE_STEP(As[0], Bs[0], "8");
    MOE_STAGE(As[3], Bs[3], 4064); MOE_STEP(As[1], Bs[1], "8");
    MOE_STEP(As[2], Bs[2], "4");
    MOE_STEP(As[3], Bs[3], "0");

    const float* b2e = b2 + (size_t)e * D_;
#pragma unroll
    for (int mt = 0; mt < 4; mt++)
#pragma unroll
        for (int nt = 0; nt < 4; nt++) {
            int gn = n0 + wn * 64 + nt * 16 + l15;
            float bias = b2e[gn];
#pragma unroll
            for (int r = 0; r < 4; r++) {
                int gm = m0 + wm * 64 + mt * 16 + qd * 4 + r;
                y[(size_t)gm * D_ + gn] = acc[mt][nt][r] + bias;
            }
        }
}

// combine: out[tok] += g0*y[s0] + g1*y[s1]. One block per token.
__global__ __launch_bounds__(256) void combine_k(const float* __restrict__ y,
                                                 const int* __restrict__ sidx,
                                                 const float* __restrict__ tgate,
                                                 float* __restrict__ out) {
    int tok = blockIdx.x;
    int d = threadIdx.x * 4;
    int s0 = sidx[tok * 2], s1 = sidx[tok * 2 + 1];
    float g0 = tgate[tok * 2], g1 = tgate[tok * 2 + 1];
    float4 a = *(const float4*)(y + (size_t)s0 * D_ + d);
    float4 b = *(const float4*)(y + (size_t)s1 * D_ + d);
    float4 o = *(const float4*)(out + (size_t)tok * D_ + d);
    o.x += g0 * a.x + g1 * b.x;
    o.y += g0 * a.y + g1 * b.y;
    o.z += g0 * a.z + g1 * b.z;
    o.w += g0 * a.w + g1 * b.w;
    *(float4*)(out + (size_t)tok * D_ + d) = o;
}

// ---------------------------------------------------------------------------
extern "C" void kernel_launch(void* const* d_in, const int* in_sizes, int n_in,
                              void* d_out, int out_size, void* d_ws, size_t ws_size,
                              hipStream_t stream) {
    const float* x   = (const float*)d_in[0];
    const float* anw = (const float*)d_in[1];
    const float* wq  = (const float*)d_in[2];
    const float* wk  = (const float*)d_in[3];
    const float* wv  = (const float*)d_in[4];
    const float* wo  = (const float*)d_in[5];
    const float* mnw = (const float*)d_in[6];
    const float* rw  = (const float*)d_in[7];
    const float* w1  = (const float*)d_in[8];
    const float* b1  = (const float*)d_in[9];
    const float* w2  = (const float*)d_in[10];
    const float* b2  = (const float*)d_in[11];
    float* out = (float*)d_out;

    char* p = (char*)d_ws;
    auto take = [&](size_t n) { char* r = p; p += (n + 255) & ~(size_t)255; return r; };
    bf16* h1h = (bf16*)take((size_t)OUTN * 2);
    bf16* h1l = (bf16*)take((size_t)OUTN * 2);
    bf16* qh  = (bf16*)take((size_t)OUTN * 2);
    bf16* ql  = (bf16*)take((size_t)OUTN * 2);
    bf16* kh  = (bf16*)take((size_t)OUTN * 2);
    bf16* kl  = (bf16*)take((size_t)OUTN * 2);
    bf16* vh  = (bf16*)take((size_t)OUTN * 2);
    bf16* vl  = (bf16*)take((size_t)OUTN * 2);
    bf16* vth = (bf16*)take((size_t)OUTN * 2);   // V^T [(b*16+h)*64+dh][S]
    bf16* vtl = (bf16*)take((size_t)OUTN * 2);
    bf16* wqth = (bf16*)take((size_t)D_ * D_ * 2);
    bf16* wqtl = (bf16*)take((size_t)D_ * D_ * 2);
    bf16* wkth = (bf16*)take((size_t)D_ * D_ * 2);
    bf16* wktl = (bf16*)take((size_t)D_ * D_ * 2);
    bf16* wvth = (bf16*)take((size_t)D_ * D_ * 2);
    bf16* wvtl = (bf16*)take((size_t)D_ * D_ * 2);
    bf16* woth = (bf16*)take((size_t)D_ * D_ * 2);
    bf16* wotl = (bf16*)take((size_t)D_ * D_ * 2);
    bf16* w1t = (bf16*)take((size_t)NE * FF_ * D_ * 2);
    bf16* w2t = (bf16*)take((size_t)NE * FF_ * D_ * 2);
    bf16* act = (bf16*)take((size_t)CAP * FF_ * 2);
    int*   tidx  = (int*)take(NTOK * 2 * 4);
    float* tgate = (float*)take(NTOK * 2 * 4);
    int*   sidx  = (int*)take(NTOK * 2 * 4);
    int*   ecnt  = (int*)take(64);
    int*   ecnt2 = (int*)take(64);
    float* psum  = (float*)take(64);
    int*   eoffp = (int*)take(64);
    int*   stok  = (int*)take(CAP * 4);

    // aliases over dead buffers:
    bf16*  aoh = h1h;            // h1 dead after QKV gemm
    bf16*  aol = h1l;
    float* h_f = (float*)qh;     // q dead after attention (spans qh+ql, 8 MB)
    bf16*  h_b = kh;             // k dead after attention
    float* y   = (float*)vh;     // v + vth splits dead after attention: 8+8=16 MB... plus vl; >= CAP*D*4=21 MB (vh+vl+vth = 12 MB? vh,vl,vth,vtl = 16 MB < 21) — use vh..vtl span: 16 MB + wq splits 4 MB = 21 MB OK

    hipMemsetAsync(ecnt, 0, NE * 4, stream);
    hipMemsetAsync(psum, 0, NE * 4, stream);
    hipMemsetAsync(stok, 0, CAP * 4, stream);
    // preload out with X (WO accumulates into it via atomics, split-K=4)
    hipMemcpyAsync(out, x, (size_t)OUTN * 4, hipMemcpyDeviceToDevice, stream);

    // weight transposes
    trans_split_k<<<dim3(32, 32, 4), 256, 0, stream>>>(wq, wk, wv, wo,
        wqth, wqtl, wkth, wktl, wvth, wvtl, woth, wotl);
    transpose_cast4_k<<<dim3(FF_ / 64, D_ / 64, NE), 256, 0, stream>>>(w1, w1t, D_, FF_);
    transpose_cast4_k<<<dim3(D_ / 64, FF_ / 64, NE), 256, 0, stream>>>(w2, w2t, FF_, D_);

    // attention path (split-bf16 MFMA, fp32 fidelity for router)
    rmsnorm_k<<<NTOK, 256, 0, stream>>>(x, anw, nullptr, h1h, h1l);
    gemm_qkv_k<<<dim3(16, 24), 256, 0, stream>>>(h1h, h1l,
        wqth, wqtl, wkth, wktl, wvth, wvtl, qh, ql, kh, kl, vh, vl);
    vtrans_k<<<dim3(S_ / 64, 32, 2), 256, 0, stream>>>(vh, vl, vth, vtl);
    attn_mfma_k<<<dim3(16, 16, 2), 256, 0, stream>>>(qh, ql, kh, kl, vth, vtl, aoh, aol);
    gemm_wo_k<<<dim3(16, 8, 4), 256, 0, stream>>>(aoh, aol, woth, wotl, out);

    // MoE
    rmsnorm_k<<<NTOK, 256, 0, stream>>>(out, mnw, h_f, h_b, nullptr);
    router_k<<<NTOK / 4, 256, 0, stream>>>(h_f, rw, tidx, tgate, ecnt, psum);
    passb_k<<<1, 64, 0, stream>>>(ecnt, psum, eoffp, ecnt2, out + OUTN);
    scatter_k<<<NTOK / 256, 256, 0, stream>>>(tidx, eoffp, ecnt2, stok, sidx);
    moe_gemm1_k<<<dim3(CAP / 128, FF_ / 128), 256, 0, stream>>>(h_b, w1t, b1, eoffp, stok, act);
    moe_gemm2_k<<<dim3(CAP / 128, D_ / 128), 256, 0, stream>>>(act, w2t, b2, eoffp, y);
    combine_k<<<NTOK, 256, 0, stream>>>(y, sidx, tgate, out);
}